// Round 4
// baseline (4669.903 us; speedup 1.0000x reference)
//
#include <hip/hip_runtime.h>
#include <hip/hip_bf16.h>

#define NN  50000
#define EE  320000
#define E2  (EE + NN)
#define DIN 128
#define DD  256

typedef __attribute__((ext_vector_type(8))) short    bf16x8;
typedef __attribute__((ext_vector_type(4))) float    f32x4;

// ---------------- helpers ----------------

static __device__ __forceinline__ float bf2f(unsigned short u) {
  return __builtin_bit_cast(float, (unsigned)u << 16);
}

static __device__ __forceinline__ unsigned short f2bf(float f) {
  unsigned u = __builtin_bit_cast(unsigned, f);
  return (unsigned short)((u + 0x7fffu + ((u >> 16) & 1u)) >> 16);
}

// ---------------- weight/activation cast fp32 -> bf16 ----------------

__global__ void k_cast(const float* __restrict__ in, unsigned short* __restrict__ out, int n) {
  int i = blockIdx.x * blockDim.x + threadIdx.x;
  if (i >= n) return;
  out[i] = f2bf(in[i]);
}

// ---------------- CSR build ----------------

__global__ void k_deg(const int* __restrict__ ei, int* __restrict__ deg) {
  int i = blockIdx.x * blockDim.x + threadIdx.x;
  if (i >= E2) return;
  int dst = (i < EE) ? ei[EE + i] : (i - EE);
  atomicAdd(&deg[dst], 1);
}

__global__ __launch_bounds__(1024) void k_scan_tile(const int* __restrict__ in,
                                                    int* __restrict__ out,
                                                    int* __restrict__ tsum, int n) {
  __shared__ int sm[1024];
  int tid = threadIdx.x;
  int g = blockIdx.x * 1024 + tid;
  sm[tid] = (g < n) ? in[g] : 0;
  __syncthreads();
  for (int off = 1; off < 1024; off <<= 1) {
    int t = (tid >= off) ? sm[tid - off] : 0;
    __syncthreads();
    sm[tid] += t;
    __syncthreads();
  }
  if (g < n) out[g] = sm[tid];
  if (tid == 1023) tsum[blockIdx.x] = sm[1023];
}

__global__ void k_scan_sums(int* __restrict__ tsum, int nb) {
  int tid = threadIdx.x;           // single wave of 64, nb <= 64
  int v = (tid < nb) ? tsum[tid] : 0;
  for (int off = 1; off < 64; off <<= 1) {
    int t = __shfl_up(v, off);
    if (tid >= off) v += t;
  }
  if (tid < nb) tsum[tid] = v;
}

__global__ void k_scan_add(int* __restrict__ out, const int* __restrict__ tsum, int n) {
  int g = blockIdx.x * blockDim.x + threadIdx.x;
  if (g >= n || g < 1024) return;
  out[g] += tsum[(g >> 10) - 1];
}

__global__ void k_scatter(const int* __restrict__ ei, const int* __restrict__ deg,
                          const int* __restrict__ inc, int* __restrict__ cur,
                          int* __restrict__ ssrc) {
  int i = blockIdx.x * blockDim.x + threadIdx.x;
  if (i >= E2) return;
  int src, dst;
  if (i < EE) { src = ei[i]; dst = ei[EE + i]; } else { src = dst = i - EE; }
  int pos = atomicAdd(&cur[dst], 1);
  ssrc[inc[dst] - deg[dst] + pos] = src;
}

// ---------------- GAT pieces (h is bf16 now) ----------------

__global__ __launch_bounds__(256) void k_dots(const unsigned short* __restrict__ hb,
                                              const float* __restrict__ asrc,
                                              const float* __restrict__ adst,
                                              float* __restrict__ hs, float* __restrict__ hd) {
  int node = blockIdx.x * 4 + (threadIdx.x >> 6);
  if (node >= NN) return;
  int lane = threadIdx.x & 63;
  ushort4 hv = *reinterpret_cast<const ushort4*>(hb + (size_t)node * DD + lane * 4);
  float v0 = bf2f(hv.x), v1 = bf2f(hv.y), v2 = bf2f(hv.z), v3 = bf2f(hv.w);
  const float* as = asrc + lane * 4;
  const float* ad = adst + lane * 4;
  float s1 = v0 * as[0] + v1 * as[1] + v2 * as[2] + v3 * as[3];
  float s2 = v0 * ad[0] + v1 * ad[1] + v2 * ad[2] + v3 * ad[3];
  for (int off = 32; off; off >>= 1) {
    s1 += __shfl_xor(s1, off);
    s2 += __shfl_xor(s2, off);
  }
  if (lane == 0) { hs[node] = s1; hd[node] = s2; }
}

__global__ void k_esoft(const int* __restrict__ ssrc, const int* __restrict__ deg,
                        const int* __restrict__ inc, const float* __restrict__ hs,
                        const float* __restrict__ hd, float* __restrict__ alpha) {
  int d = blockIdx.x * blockDim.x + threadIdx.x;
  if (d >= NN) return;
  int end = inc[d], cnt = deg[d], base = end - cnt;
  float hdd = hd[d];
  float m = -1e30f;
  for (int i = 0; i < cnt; ++i) {
    float s = hs[ssrc[base + i]] + hdd;
    s = (s < 0.f) ? 0.2f * s : s;
    alpha[base + i] = s;
    m = fmaxf(m, s);
  }
  float sum = 0.f;
  for (int i = 0; i < cnt; ++i) {
    float e = __expf(alpha[base + i] - m);
    alpha[base + i] = e;
    sum += e;
  }
  float inv = 1.f / sum;
  for (int i = 0; i < cnt; ++i) alpha[base + i] *= inv;
}

// one wave per dst node; lane handles 4 columns via 8B loads
__global__ __launch_bounds__(256) void k_agg(const unsigned short* __restrict__ hb,
                                             const int* __restrict__ ssrc,
                                             const int* __restrict__ deg,
                                             const int* __restrict__ inc,
                                             const float* __restrict__ alpha,
                                             const float* __restrict__ bias,
                                             unsigned short* __restrict__ out) {
  int d = blockIdx.x * 4 + (threadIdx.x >> 6);
  if (d >= NN) return;
  int lane = threadIdx.x & 63;
  int end = inc[d], cnt = deg[d], base = end - cnt;
  float a0 = 0.f, a1 = 0.f, a2 = 0.f, a3 = 0.f;
  for (int i = 0; i < cnt; ++i) {
    int s = ssrc[base + i];
    float a = alpha[base + i];
    ushort4 hv = *reinterpret_cast<const ushort4*>(hb + (size_t)s * DD + lane * 4);
    a0 += a * bf2f(hv.x);
    a1 += a * bf2f(hv.y);
    a2 += a * bf2f(hv.z);
    a3 += a * bf2f(hv.w);
  }
  const float* bp = bias + lane * 4;
  float r0 = a0 + bp[0], r1 = a1 + bp[1], r2 = a2 + bp[2], r3 = a3 + bp[3];
  ushort4 o;
  o.x = f2bf(r0 > 0.f ? r0 : 0.f);
  o.y = f2bf(r1 > 0.f ? r1 : 0.f);
  o.z = f2bf(r2 > 0.f ? r2 : 0.f);
  o.w = f2bf(r3 > 0.f ? r3 : 0.f);
  *reinterpret_cast<ushort4*>(out + (size_t)d * DD + lane * 4) = o;
}

// ---------------- register-resident skinny-K GEMMs (no LDS, no barriers) ----------------
// Layout per wave: A-frag A[m=lane&15][k=quad*8+j]; C/D col=lane&15, row=quad*4+r.

// Variant 1: N = 256 fixed (acc-resident), K = KC*32 per group, loops K-groups.
// C = act(A @ B^T + bias [+ R]) -> bf16. Block: 4 waves x 32 rows = 128 rows.
template<int KC>
__global__ __launch_bounds__(256) void k_gemm_k(
    const unsigned short* __restrict__ A, int lda,
    const unsigned short* __restrict__ B,           // [256 x K]
    const float* __restrict__ bias,
    const unsigned short* __restrict__ R, int ldr,
    unsigned short* __restrict__ C, int ldc,
    int M, int K, int act) {
  const int lane = threadIdx.x & 63;
  const int w    = threadIdx.x >> 6;
  const int ml   = lane & 15;
  const int quad = lane >> 4;
  const int m0   = blockIdx.x * 128 + w * 32;
  int r0 = m0 + ml;      if (r0 >= M) r0 = M - 1;
  int r1 = m0 + 16 + ml; if (r1 >= M) r1 = M - 1;
  const unsigned short* A0 = A + (size_t)r0 * lda + quad * 8;
  const unsigned short* A1 = A + (size_t)r1 * lda + quad * 8;

  f32x4 acc[2][16] = {};

  for (int kg = 0; kg < K; kg += KC * 32) {
    bf16x8 af0[KC], af1[KC];
#pragma unroll
    for (int k = 0; k < KC; ++k) {
      af0[k] = *reinterpret_cast<const bf16x8*>(A0 + kg + k * 32);
      af1[k] = *reinterpret_cast<const bf16x8*>(A1 + kg + k * 32);
    }
#pragma unroll
    for (int j = 0; j < 16; ++j) {
      const unsigned short* Bj = B + (size_t)(j * 16 + ml) * K + kg + quad * 8;
#pragma unroll
      for (int k = 0; k < KC; ++k) {
        bf16x8 bb = *reinterpret_cast<const bf16x8*>(Bj + k * 32);
        acc[0][j] = __builtin_amdgcn_mfma_f32_16x16x32_bf16(af0[k], bb, acc[0][j], 0, 0, 0);
        acc[1][j] = __builtin_amdgcn_mfma_f32_16x16x32_bf16(af1[k], bb, acc[1][j], 0, 0, 0);
      }
    }
  }

#pragma unroll
  for (int i = 0; i < 2; ++i)
#pragma unroll
    for (int j = 0; j < 16; ++j) {
      int col = j * 16 + ml;
      float bv = bias ? bias[col] : 0.f;
#pragma unroll
      for (int r = 0; r < 4; ++r) {
        int row = m0 + i * 16 + quad * 4 + r;
        if (row < M) {
          float v = acc[i][j][r] + bv;
          if (R) v += bf2f(R[(size_t)row * ldr + col]);
          if (act) v = v > 0.f ? v : 0.f;
          C[(size_t)row * ldc + col] = f2bf(v);
        }
      }
    }
}

// Variant 2: K = 256 fixed (A-frags hoisted), loops N-tiles of 128 cols.
// grid.x = nsplit (n-tile stride), grid.y = M/128.
__global__ __launch_bounds__(256) void k_gemm_n(
    const unsigned short* __restrict__ A,           // lda = 256
    const unsigned short* __restrict__ B,           // [N x 256]
    const float* __restrict__ bias,
    unsigned short* __restrict__ C, int ldc,
    int M, int N, int act) {
  const int lane = threadIdx.x & 63;
  const int w    = threadIdx.x >> 6;
  const int ml   = lane & 15;
  const int quad = lane >> 4;
  const int m0   = blockIdx.y * 128 + w * 32;
  int r0 = m0 + ml;      if (r0 >= M) r0 = M - 1;
  int r1 = m0 + 16 + ml; if (r1 >= M) r1 = M - 1;
  const unsigned short* A0 = A + (size_t)r0 * 256 + quad * 8;
  const unsigned short* A1 = A + (size_t)r1 * 256 + quad * 8;

  bf16x8 af0[8], af1[8];
#pragma unroll
  for (int k = 0; k < 8; ++k) {
    af0[k] = *reinterpret_cast<const bf16x8*>(A0 + k * 32);
    af1[k] = *reinterpret_cast<const bf16x8*>(A1 + k * 32);
  }

  const int ntiles = N >> 7;
  for (int nt = blockIdx.x; nt < ntiles; nt += gridDim.x) {
    f32x4 acc[2][8] = {};
#pragma unroll
    for (int j = 0; j < 8; ++j) {
      const unsigned short* Bj = B + (size_t)(nt * 128 + j * 16 + ml) * 256 + quad * 8;
#pragma unroll
      for (int k = 0; k < 8; ++k) {
        bf16x8 bb = *reinterpret_cast<const bf16x8*>(Bj + k * 32);
        acc[0][j] = __builtin_amdgcn_mfma_f32_16x16x32_bf16(af0[k], bb, acc[0][j], 0, 0, 0);
        acc[1][j] = __builtin_amdgcn_mfma_f32_16x16x32_bf16(af1[k], bb, acc[1][j], 0, 0, 0);
      }
    }
#pragma unroll
    for (int i = 0; i < 2; ++i)
#pragma unroll
      for (int j = 0; j < 8; ++j) {
        int col = nt * 128 + j * 16 + ml;
        float bv = bias[col];
#pragma unroll
        for (int r = 0; r < 4; ++r) {
          int row = m0 + i * 16 + quad * 4 + r;
          if (row < M) {
            float v = acc[i][j][r] + bv;
            if (act) v = v > 0.f ? v : 0.f;
            C[(size_t)row * ldc + col] = f2bf(v);
          }
        }
      }
  }
}

// ---------------- transformer pieces (bf16 activations, dense layouts) ----------------

__global__ void k_seqbuild(const unsigned short* __restrict__ x1,
                           const unsigned short* __restrict__ x2,
                           const float* __restrict__ cls, const float* __restrict__ pos,
                           unsigned short* __restrict__ seqc, int n0, int cn) {
  int idx = blockIdx.x * blockDim.x + threadIdx.x;
  int total = cn * 3 * DD;
  if (idx >= total) return;
  int c = idx & (DD - 1);
  int r = idx >> 8;
  int t = r % 3, ln = r / 3;
  int n = n0 + ln;
  float v;
  if (t == 0)      v = cls[c];
  else if (t == 1) v = bf2f(x1[(size_t)n * DD + c]);
  else             v = bf2f(x2[(size_t)n * DD + c]);
  seqc[idx] = f2bf(v + pos[t * DD + c]);
}

// qkv: [3 rows x 768] per node (dense); o -> obuf [3 rows x 256]
__global__ __launch_bounds__(256) void k_attn(const unsigned short* __restrict__ qkvb,
                                              unsigned short* __restrict__ obuf) {
  __shared__ float qkv[3][768];
  __shared__ float lg[4][3][3];
  __shared__ float aw[4][3][3];
  int tid = threadIdx.x;
  size_t r0 = (size_t)blockIdx.x * 3;
  for (int i = tid; i < 3 * 768; i += 256) {
    int r = i / 768, c = i % 768;
    qkv[r][c] = bf2f(qkvb[(r0 + r) * 768 + c]);
  }
  __syncthreads();
  int h = tid >> 6, lane = tid & 63;
#pragma unroll
  for (int ti = 0; ti < 3; ++ti)
#pragma unroll
    for (int j = 0; j < 3; ++j) {
      float p = qkv[ti][h * 64 + lane] * qkv[j][256 + h * 64 + lane];
      for (int off = 32; off; off >>= 1) p += __shfl_xor(p, off);
      if (lane == 0) lg[h][ti][j] = p * 0.125f;
    }
  __syncthreads();
  if (lane < 3) {
    int ti = lane;
    float l0 = lg[h][ti][0], l1 = lg[h][ti][1], l2 = lg[h][ti][2];
    float m = fmaxf(l0, fmaxf(l1, l2));
    float e0 = __expf(l0 - m), e1 = __expf(l1 - m), e2 = __expf(l2 - m);
    float inv = 1.f / (e0 + e1 + e2);
    aw[h][ti][0] = e0 * inv; aw[h][ti][1] = e1 * inv; aw[h][ti][2] = e2 * inv;
  }
  __syncthreads();
  int c = tid;
#pragma unroll
  for (int ti = 0; ti < 3; ++ti) {
    float o = aw[h][ti][0] * qkv[0][512 + c] +
              aw[h][ti][1] * qkv[1][512 + c] +
              aw[h][ti][2] * qkv[2][512 + c];
    obuf[(r0 + ti) * 256 + c] = f2bf(o);
  }
}

__global__ __launch_bounds__(256) void k_ln(unsigned short* __restrict__ buf, int rows,
                                            const float* __restrict__ g,
                                            const float* __restrict__ b) {
  int row = blockIdx.x * 4 + (threadIdx.x >> 6);
  if (row >= rows) return;
  int lane = threadIdx.x & 63;
  unsigned short* p = buf + (size_t)row * DD;
  float v[4];
  float s = 0.f, s2 = 0.f;
#pragma unroll
  for (int i = 0; i < 4; ++i) {
    v[i] = bf2f(p[i * 64 + lane]);
    s += v[i]; s2 += v[i] * v[i];
  }
  for (int off = 32; off; off >>= 1) { s += __shfl_xor(s, off); s2 += __shfl_xor(s2, off); }
  float mean = s * (1.f / 256.f);
  float var  = s2 * (1.f / 256.f) - mean * mean;
  float inv  = rsqrtf(var + 1e-5f);
#pragma unroll
  for (int i = 0; i < 4; ++i) {
    int c = i * 64 + lane;
    p[c] = f2bf((v[i] - mean) * inv * g[c] + b[c]);
  }
}

__global__ __launch_bounds__(256) void k_final(const unsigned short* __restrict__ seqc,
                                               int n0, int cn,
                                               const float* __restrict__ g,
                                               const float* __restrict__ b,
                                               float* __restrict__ out) {
  int ln = blockIdx.x * 4 + (threadIdx.x >> 6);
  if (ln >= cn) return;
  int lane = threadIdx.x & 63;
  const unsigned short* p = seqc + (size_t)ln * 3 * DD;   // token 0 row
  float v[4];
  float s = 0.f, s2 = 0.f;
#pragma unroll
  for (int i = 0; i < 4; ++i) {
    v[i] = bf2f(p[i * 64 + lane]);
    s += v[i]; s2 += v[i] * v[i];
  }
  for (int off = 32; off; off >>= 1) { s += __shfl_xor(s, off); s2 += __shfl_xor(s2, off); }
  float mean = s * (1.f / 256.f);
  float var  = s2 * (1.f / 256.f) - mean * mean;
  float inv  = rsqrtf(var + 1e-5f);
#pragma unroll
  for (int i = 0; i < 4; ++i) {
    int c = i * 64 + lane;
    out[(size_t)(n0 + ln) * DD + c] = (v[i] - mean) * inv * g[c] + b[c];
  }
}

// ---------------- host ----------------

extern "C" void kernel_launch(void* const* d_in, const int* in_sizes, int n_in,
                              void* d_out, int out_size, void* d_ws, size_t ws_size,
                              hipStream_t stream) {
  const float* x       = (const float*)d_in[0];
  const int*   ei      = (const int*)d_in[1];
  const float* gat1_W  = (const float*)d_in[2];
  const float* gat1_b  = (const float*)d_in[3];
  const float* gat1_as = (const float*)d_in[4];
  const float* gat1_ad = (const float*)d_in[5];
  const float* gat2_W  = (const float*)d_in[6];
  const float* gat2_b  = (const float*)d_in[7];
  const float* gat2_as = (const float*)d_in[8];
  const float* gat2_ad = (const float*)d_in[9];
  const float* cls     = (const float*)d_in[10];
  const float* pos     = (const float*)d_in[11];
  const float* Wqkv    = (const float*)d_in[12];
  const float* bqkv    = (const float*)d_in[13];
  const float* Wo      = (const float*)d_in[14];
  const float* bo      = (const float*)d_in[15];
  const float* ln1_g   = (const float*)d_in[16];
  const float* ln1_b   = (const float*)d_in[17];
  const float* ln2_g   = (const float*)d_in[18];
  const float* ln2_b   = (const float*)d_in[19];
  const float* Wff1    = (const float*)d_in[20];
  const float* bff1    = (const float*)d_in[21];
  const float* Wff2    = (const float*)d_in[22];
  const float* bff2    = (const float*)d_in[23];
  const float* norm_g  = (const float*)d_in[24];
  const float* norm_b  = (const float*)d_in[25];
  float* out = (float*)d_out;

  char* ws = (char*)d_ws;
  size_t off = 0;
  auto alloc = [&](size_t bytes) -> void* {
    off = (off + 255) & ~(size_t)255;
    void* p = ws + off;
    off += bytes;
    return p;
  };

  unsigned short* wb_g1  = (unsigned short*)alloc(sizeof(unsigned short) * 256 * 128);
  unsigned short* wb_g2  = (unsigned short*)alloc(sizeof(unsigned short) * 256 * 256);
  unsigned short* wb_qkv = (unsigned short*)alloc(sizeof(unsigned short) * 2 * 768 * 256);
  unsigned short* wb_o   = (unsigned short*)alloc(sizeof(unsigned short) * 2 * 256 * 256);
  unsigned short* wb_f1  = (unsigned short*)alloc(sizeof(unsigned short) * 2 * 1024 * 256);
  unsigned short* wb_f2  = (unsigned short*)alloc(sizeof(unsigned short) * 2 * 256 * 1024);
  unsigned short* xb  = (unsigned short*)alloc(sizeof(unsigned short) * (size_t)NN * DIN);
  unsigned short* hb  = (unsigned short*)alloc(sizeof(unsigned short) * (size_t)NN * DD);
  unsigned short* x1b = (unsigned short*)alloc(sizeof(unsigned short) * (size_t)NN * DD);
  unsigned short* x2b = (unsigned short*)alloc(sizeof(unsigned short) * (size_t)NN * DD);
  float* hs  = (float*)alloc(sizeof(float) * NN);
  float* hd  = (float*)alloc(sizeof(float) * NN);
  int* deg   = (int*)alloc(sizeof(int) * NN);
  int* inc   = (int*)alloc(sizeof(int) * NN);
  int* cur   = (int*)alloc(sizeof(int) * NN);
  int* tsum  = (int*)alloc(sizeof(int) * 64);
  int* ssrc  = (int*)alloc(sizeof(int) * E2);
  float* alpha = (float*)alloc(sizeof(float) * E2);

  // transformer chunking: keep per-chunk activations L3-resident (~173 MB @ 12500)
  size_t fixed = (off + 255) & ~(size_t)255;
  size_t rem = (ws_size > fixed + 4096) ? (ws_size - fixed - 4096) : 0;
  const size_t per_node = (size_t)3 * (256 + 768 + 256 + 1024) * 2;
  size_t cn_max = rem / per_node;
  if (cn_max < 1) cn_max = 1;
  if (cn_max > 12500) cn_max = 12500;
  int nc = (int)((NN + cn_max - 1) / cn_max);
  int cn = (NN + nc - 1) / nc;
  unsigned short* seqc = (unsigned short*)alloc(sizeof(unsigned short) * (size_t)3 * cn * 256);
  unsigned short* qkvb = (unsigned short*)alloc(sizeof(unsigned short) * (size_t)3 * cn * 768);
  unsigned short* obuf = (unsigned short*)alloc(sizeof(unsigned short) * (size_t)3 * cn * 256);
  unsigned short* ffb  = (unsigned short*)alloc(sizeof(unsigned short) * (size_t)3 * cn * 1024);

  // ---- casts ----
  auto cast = [&](const float* src, unsigned short* dst, int n) {
    k_cast<<<(n + 255) / 256, 256, 0, stream>>>(src, dst, n);
  };
  cast(gat1_W, wb_g1, 256 * 128);
  cast(gat2_W, wb_g2, 256 * 256);
  cast(Wqkv, wb_qkv, 2 * 768 * 256);
  cast(Wo, wb_o, 2 * 256 * 256);
  cast(Wff1, wb_f1, 2 * 1024 * 256);
  cast(Wff2, wb_f2, 2 * 256 * 1024);
  cast(x, xb, NN * DIN);

  // ---- CSR build ----
  hipMemsetAsync(deg, 0, sizeof(int) * NN, stream);
  hipMemsetAsync(cur, 0, sizeof(int) * NN, stream);
  k_deg<<<(E2 + 255) / 256, 256, 0, stream>>>(ei, deg);
  int nb = (NN + 1023) / 1024;
  k_scan_tile<<<nb, 1024, 0, stream>>>(deg, inc, tsum, NN);
  k_scan_sums<<<1, 64, 0, stream>>>(tsum, nb);
  k_scan_add<<<(NN + 255) / 256, 256, 0, stream>>>(inc, tsum, NN);
  k_scatter<<<(E2 + 255) / 256, 256, 0, stream>>>(ei, deg, inc, cur, ssrc);

  // ---- GAT layer 1: hb = xb @ W1^T (K=128) ----
  k_gemm_k<4><<<(NN + 127) / 128, 256, 0, stream>>>(
      xb, DIN, wb_g1, nullptr, nullptr, 0, hb, DD, NN, DIN, 0);
  k_dots<<<(NN + 3) / 4, 256, 0, stream>>>(hb, gat1_as, gat1_ad, hs, hd);
  k_esoft<<<(NN + 255) / 256, 256, 0, stream>>>(ssrc, deg, inc, hs, hd, alpha);
  k_agg<<<(NN + 3) / 4, 256, 0, stream>>>(hb, ssrc, deg, inc, alpha, gat1_b, x1b);

  // ---- GAT layer 2: hb = x1b @ W2^T (K=256) ----
  k_gemm_k<8><<<(NN + 127) / 128, 256, 0, stream>>>(
      x1b, DD, wb_g2, nullptr, nullptr, 0, hb, DD, NN, DD, 0);
  k_dots<<<(NN + 3) / 4, 256, 0, stream>>>(hb, gat2_as, gat2_ad, hs, hd);
  k_esoft<<<(NN + 255) / 256, 256, 0, stream>>>(ssrc, deg, inc, hs, hd, alpha);
  k_agg<<<(NN + 3) / 4, 256, 0, stream>>>(hb, ssrc, deg, inc, alpha, gat2_b, x2b);

  // ---- transformer (chunked; chunk activations stay L3-resident) ----
  for (int n0 = 0; n0 < NN; n0 += cn) {
    int c = NN - n0 < cn ? NN - n0 : cn;
    int Mch = 3 * c;
    int mblk = (Mch + 127) / 128;
    k_seqbuild<<<(c * 3 * DD + 255) / 256, 256, 0, stream>>>(x1b, x2b, cls, pos, seqc, n0, c);
    for (int l = 0; l < 2; ++l) {
      // qkv: N=768, K=256
      {
        dim3 grid(2, mblk);
        k_gemm_n<<<grid, 256, 0, stream>>>(seqc, wb_qkv + (size_t)l * 768 * 256,
                                           bqkv + l * 768, qkvb, 768, Mch, 768, 0);
      }
      k_attn<<<c, 256, 0, stream>>>(qkvb, obuf);
      // o-proj: N=256, K=256, residual = seqc
      k_gemm_k<8><<<mblk, 256, 0, stream>>>(
          obuf, DD, wb_o + (size_t)l * 256 * 256, bo + l * 256,
          seqc, DD, seqc, DD, Mch, DD, 0);
      k_ln<<<(Mch + 3) / 4, 256, 0, stream>>>(seqc, Mch, ln1_g + l * 256, ln1_b + l * 256);
      // ff1: N=1024, K=256, relu
      {
        dim3 grid(2, mblk);
        k_gemm_n<<<grid, 256, 0, stream>>>(seqc, wb_f1 + (size_t)l * 1024 * 256,
                                           bff1 + l * 1024, ffb, 1024, Mch, 1024, 1);
      }
      // ff2: N=256, K=1024, residual = seqc
      k_gemm_k<8><<<mblk, 256, 0, stream>>>(
          ffb, 1024, wb_f2 + (size_t)l * 256 * 1024, bff2 + l * 256,
          seqc, DD, seqc, DD, Mch, 1024, 0);
      k_ln<<<(Mch + 3) / 4, 256, 0, stream>>>(seqc, Mch, ln2_g + l * 256, ln2_b + l * 256);
    }
    k_final<<<(c + 3) / 4, 256, 0, stream>>>(seqc, n0, c, norm_g, norm_b, out);
  }
}

// Round 5
// 2907.709 us; speedup vs baseline: 1.6060x; 1.6060x over previous
//
#include <hip/hip_runtime.h>
#include <hip/hip_bf16.h>

#define NN  50000
#define EE  320000
#define E2  (EE + NN)
#define DIN 128
#define DD  256

typedef __attribute__((ext_vector_type(8))) short    bf16x8;
typedef __attribute__((ext_vector_type(4))) float    f32x4;

// ---------------- helpers ----------------

static __device__ __forceinline__ float bf2f(unsigned short u) {
  return __builtin_bit_cast(float, (unsigned)u << 16);
}

static __device__ __forceinline__ unsigned short f2bf(float f) {
  unsigned u = __builtin_bit_cast(unsigned, f);
  return (unsigned short)((u + 0x7fffu + ((u >> 16) & 1u)) >> 16);
}

static __device__ __forceinline__ void load_lds16(const void* g, void* l) {
  __builtin_amdgcn_global_load_lds(
      (const __attribute__((address_space(1))) void*)g,
      (__attribute__((address_space(3))) void*)l, 16, 0, 0);
}

// ---------------- weight/activation cast fp32 -> bf16 ----------------

__global__ void k_cast(const float* __restrict__ in, unsigned short* __restrict__ out, int n) {
  int i = blockIdx.x * blockDim.x + threadIdx.x;
  if (i >= n) return;
  out[i] = f2bf(in[i]);
}

// ---------------- CSR build ----------------

__global__ void k_deg(const int* __restrict__ ei, int* __restrict__ deg) {
  int i = blockIdx.x * blockDim.x + threadIdx.x;
  if (i >= E2) return;
  int dst = (i < EE) ? ei[EE + i] : (i - EE);
  atomicAdd(&deg[dst], 1);
}

__global__ __launch_bounds__(1024) void k_scan_tile(const int* __restrict__ in,
                                                    int* __restrict__ out,
                                                    int* __restrict__ tsum, int n) {
  __shared__ int sm[1024];
  int tid = threadIdx.x;
  int g = blockIdx.x * 1024 + tid;
  sm[tid] = (g < n) ? in[g] : 0;
  __syncthreads();
  for (int off = 1; off < 1024; off <<= 1) {
    int t = (tid >= off) ? sm[tid - off] : 0;
    __syncthreads();
    sm[tid] += t;
    __syncthreads();
  }
  if (g < n) out[g] = sm[tid];
  if (tid == 1023) tsum[blockIdx.x] = sm[1023];
}

__global__ void k_scan_sums(int* __restrict__ tsum, int nb) {
  int tid = threadIdx.x;           // single wave of 64, nb <= 64
  int v = (tid < nb) ? tsum[tid] : 0;
  for (int off = 1; off < 64; off <<= 1) {
    int t = __shfl_up(v, off);
    if (tid >= off) v += t;
  }
  if (tid < nb) tsum[tid] = v;
}

__global__ void k_scan_add(int* __restrict__ out, const int* __restrict__ tsum, int n) {
  int g = blockIdx.x * blockDim.x + threadIdx.x;
  if (g >= n || g < 1024) return;
  out[g] += tsum[(g >> 10) - 1];
}

__global__ void k_scatter(const int* __restrict__ ei, const int* __restrict__ deg,
                          const int* __restrict__ inc, int* __restrict__ cur,
                          int* __restrict__ ssrc) {
  int i = blockIdx.x * blockDim.x + threadIdx.x;
  if (i >= E2) return;
  int src, dst;
  if (i < EE) { src = ei[i]; dst = ei[EE + i]; } else { src = dst = i - EE; }
  int pos = atomicAdd(&cur[dst], 1);
  ssrc[inc[dst] - deg[dst] + pos] = src;
}

// ---------------- GAT pieces (h in bf16) ----------------

__global__ __launch_bounds__(256) void k_dots(const unsigned short* __restrict__ hb,
                                              const float* __restrict__ asrc,
                                              const float* __restrict__ adst,
                                              float* __restrict__ hs, float* __restrict__ hd) {
  int node = blockIdx.x * 4 + (threadIdx.x >> 6);
  if (node >= NN) return;
  int lane = threadIdx.x & 63;
  ushort4 hv = *reinterpret_cast<const ushort4*>(hb + (size_t)node * DD + lane * 4);
  float v0 = bf2f(hv.x), v1 = bf2f(hv.y), v2 = bf2f(hv.z), v3 = bf2f(hv.w);
  const float* as = asrc + lane * 4;
  const float* ad = adst + lane * 4;
  float s1 = v0 * as[0] + v1 * as[1] + v2 * as[2] + v3 * as[3];
  float s2 = v0 * ad[0] + v1 * ad[1] + v2 * ad[2] + v3 * ad[3];
  for (int off = 32; off; off >>= 1) {
    s1 += __shfl_xor(s1, off);
    s2 += __shfl_xor(s2, off);
  }
  if (lane == 0) { hs[node] = s1; hd[node] = s2; }
}

// Fused edge-softmax + aggregation: one wave per dst node.
// Phase A: lanes parallel over edges -> leaky scores into LDS, wave-max, exp, wave-sum.
// Phase B: lanes = column groups; serial edge loop, alpha broadcast from LDS.
// Assumes degree <= 256 (random 370k edges over 50k nodes: max deg ~30).
__global__ __launch_bounds__(256) void k_gat(const unsigned short* __restrict__ hb,
                                             const int* __restrict__ ssrc,
                                             const int* __restrict__ deg,
                                             const int* __restrict__ inc,
                                             const float* __restrict__ hs,
                                             const float* __restrict__ hd,
                                             const float* __restrict__ bias,
                                             unsigned short* __restrict__ out) {
  __shared__ float sE[4][256];
  __shared__ int   sI[4][256];
  int w = threadIdx.x >> 6;
  int d = blockIdx.x * 4 + w;
  if (d >= NN) return;
  int lane = threadIdx.x & 63;
  int end = inc[d], cnt = deg[d], base = end - cnt;
  if (cnt > 256) cnt = 256;
  float hdd = hd[d];

  float m = -1e30f;
  for (int i0 = 0; i0 < cnt; i0 += 64) {
    int i = i0 + lane;
    float sc = -1e30f;
    if (i < cnt) {
      int s = ssrc[base + i];
      float v = hs[s] + hdd;
      sc = (v < 0.f) ? 0.2f * v : v;
      sI[w][i] = s;
      sE[w][i] = sc;
    }
    float mm = sc;
    for (int o = 32; o; o >>= 1) mm = fmaxf(mm, __shfl_xor(mm, o));
    m = fmaxf(m, mm);
  }
  float sum = 0.f;
  for (int i0 = 0; i0 < cnt; i0 += 64) {
    int i = i0 + lane;
    float e = 0.f;
    if (i < cnt) {
      e = __expf(sE[w][i] - m);
      sE[w][i] = e;
    }
    for (int o = 32; o; o >>= 1) e += __shfl_xor(e, o);
    sum += e;
  }
  float inv = 1.f / sum;

  float a0 = 0.f, a1 = 0.f, a2 = 0.f, a3 = 0.f;
  for (int i = 0; i < cnt; ++i) {
    float a = sE[w][i];
    int s = sI[w][i];
    ushort4 hv = *reinterpret_cast<const ushort4*>(hb + (size_t)s * DD + lane * 4);
    a0 += a * bf2f(hv.x);
    a1 += a * bf2f(hv.y);
    a2 += a * bf2f(hv.z);
    a3 += a * bf2f(hv.w);
  }
  const float* bp = bias + lane * 4;
  float r0 = a0 * inv + bp[0], r1 = a1 * inv + bp[1];
  float r2 = a2 * inv + bp[2], r3 = a3 * inv + bp[3];
  ushort4 o;
  o.x = f2bf(r0 > 0.f ? r0 : 0.f);
  o.y = f2bf(r1 > 0.f ? r1 : 0.f);
  o.z = f2bf(r2 > 0.f ? r2 : 0.f);
  o.w = f2bf(r3 > 0.f ? r3 : 0.f);
  *reinterpret_cast<ushort4*>(out + (size_t)d * DD + lane * 4) = o;
}

// ---------------- m97-style LDS-staged bf16 MFMA GEMM ----------------
// C = act(A @ B^T + bias [+ R]);  A bf16 [M x K] lda, B bf16 [N x K] (ldb=K),
// C bf16 [M x ldc]. 128x128 tile, BK=32, 4 waves.

__global__ __launch_bounds__(256) void k_gemm128(
    const unsigned short* __restrict__ A, int lda,
    const unsigned short* __restrict__ B,
    const float* __restrict__ bias,
    const unsigned short* __restrict__ R, int ldr,
    unsigned short* __restrict__ C, int ldc,
    int M, int N, int K, int act) {
  __shared__ unsigned short As[128 * 32];
  __shared__ unsigned short Bs[128 * 32];

  const int tid    = threadIdx.x;
  const int lane   = tid & 63;
  const int w      = tid >> 6;
  const int m_lane = lane & 15;
  const int quad   = lane >> 4;
  const int m0     = blockIdx.y * 128;
  const int n0     = blockIdx.x * 128;
  const int wm     = (w >> 1) * 64;
  const int wn     = (w & 1) * 64;

  const int idx0 = tid, idx1 = 256 + tid;
  int rowA0 = m0 + (idx0 >> 2); if (rowA0 >= M) rowA0 = M - 1;
  int rowA1 = m0 + (idx1 >> 2); if (rowA1 >= M) rowA1 = M - 1;
  const unsigned short* gA0 = A + (size_t)rowA0 * lda + (idx0 & 3) * 8;
  const unsigned short* gA1 = A + (size_t)rowA1 * lda + (idx1 & 3) * 8;
  const unsigned short* gB0 = B + (size_t)(n0 + (idx0 >> 2)) * K + (idx0 & 3) * 8;
  const unsigned short* gB1 = B + (size_t)(n0 + (idx1 >> 2)) * K + (idx1 & 3) * 8;

  unsigned short* lA0 = As + (size_t)(w * 64) * 8;
  unsigned short* lA1 = As + (size_t)(256 + w * 64) * 8;
  unsigned short* lB0 = Bs + (size_t)(w * 64) * 8;
  unsigned short* lB1 = Bs + (size_t)(256 + w * 64) * 8;

  f32x4 acc[4][4] = {};

  for (int k0 = 0; k0 < K; k0 += 32) {
    load_lds16(gA0, lA0);
    load_lds16(gA1, lA1);
    load_lds16(gB0, lB0);
    load_lds16(gB1, lB1);
    gA0 += 32; gA1 += 32; gB0 += 32; gB1 += 32;
    __syncthreads();

    bf16x8 af[4], bg[4];
#pragma unroll
    for (int i = 0; i < 4; ++i)
      af[i] = *reinterpret_cast<const bf16x8*>(As + (wm + i * 16 + m_lane) * 32 + quad * 8);
#pragma unroll
    for (int j = 0; j < 4; ++j)
      bg[j] = *reinterpret_cast<const bf16x8*>(Bs + (wn + j * 16 + m_lane) * 32 + quad * 8);
#pragma unroll
    for (int i = 0; i < 4; ++i)
#pragma unroll
      for (int j = 0; j < 4; ++j)
        acc[i][j] = __builtin_amdgcn_mfma_f32_16x16x32_bf16(af[i], bg[j], acc[i][j], 0, 0, 0);
    __syncthreads();
  }

#pragma unroll
  for (int i = 0; i < 4; ++i) {
#pragma unroll
    for (int j = 0; j < 4; ++j) {
      int col = n0 + wn + j * 16 + m_lane;
      float bv = bias ? bias[col] : 0.f;
#pragma unroll
      for (int r = 0; r < 4; ++r) {
        int row = m0 + wm + i * 16 + quad * 4 + r;
        if (row < M) {
          float v = acc[i][j][r] + bv;
          if (R) v += bf2f(R[(size_t)row * ldr + col]);
          if (act) v = v > 0.f ? v : 0.f;
          C[(size_t)row * ldc + col] = f2bf(v);
        }
      }
    }
  }
}

// ---------------- transformer pieces (bf16 activations, dense layouts) ----------------

__global__ void k_seqbuild(const unsigned short* __restrict__ x1,
                           const unsigned short* __restrict__ x2,
                           const float* __restrict__ cls, const float* __restrict__ pos,
                           unsigned short* __restrict__ seqc, int n0, int cn) {
  int idx = blockIdx.x * blockDim.x + threadIdx.x;
  int total = cn * 3 * DD;
  if (idx >= total) return;
  int c = idx & (DD - 1);
  int r = idx >> 8;
  int t = r % 3, ln = r / 3;
  int n = n0 + ln;
  float v;
  if (t == 0)      v = cls[c];
  else if (t == 1) v = bf2f(x1[(size_t)n * DD + c]);
  else             v = bf2f(x2[(size_t)n * DD + c]);
  seqc[idx] = f2bf(v + pos[t * DD + c]);
}

// qkv: [3 rows x 768] per node; attention output overwrites the q slot in place.
__global__ __launch_bounds__(256) void k_attn(unsigned short* __restrict__ qkvb) {
  __shared__ float qkv[3][768];
  __shared__ float lg[4][3][3];
  __shared__ float aw[4][3][3];
  int tid = threadIdx.x;
  size_t r0 = (size_t)blockIdx.x * 3;
  for (int i = tid; i < 3 * 768; i += 256) {
    int r = i / 768, c = i % 768;
    qkv[r][c] = bf2f(qkvb[(r0 + r) * 768 + c]);
  }
  __syncthreads();
  int h = tid >> 6, lane = tid & 63;
#pragma unroll
  for (int ti = 0; ti < 3; ++ti)
#pragma unroll
    for (int j = 0; j < 3; ++j) {
      float p = qkv[ti][h * 64 + lane] * qkv[j][256 + h * 64 + lane];
      for (int off = 32; off; off >>= 1) p += __shfl_xor(p, off);
      if (lane == 0) lg[h][ti][j] = p * 0.125f;
    }
  __syncthreads();
  if (lane < 3) {
    int ti = lane;
    float l0 = lg[h][ti][0], l1 = lg[h][ti][1], l2 = lg[h][ti][2];
    float m = fmaxf(l0, fmaxf(l1, l2));
    float e0 = __expf(l0 - m), e1 = __expf(l1 - m), e2 = __expf(l2 - m);
    float inv = 1.f / (e0 + e1 + e2);
    aw[h][ti][0] = e0 * inv; aw[h][ti][1] = e1 * inv; aw[h][ti][2] = e2 * inv;
  }
  __syncthreads();
  int c = tid;
#pragma unroll
  for (int ti = 0; ti < 3; ++ti) {
    float o = aw[h][ti][0] * qkv[0][512 + c] +
              aw[h][ti][1] * qkv[1][512 + c] +
              aw[h][ti][2] * qkv[2][512 + c];
    qkvb[(r0 + ti) * 768 + c] = f2bf(o);   // overwrite q slot
  }
}

__global__ __launch_bounds__(256) void k_ln(unsigned short* __restrict__ buf, int rows,
                                            const float* __restrict__ g,
                                            const float* __restrict__ b) {
  int row = blockIdx.x * 4 + (threadIdx.x >> 6);
  if (row >= rows) return;
  int lane = threadIdx.x & 63;
  unsigned short* p = buf + (size_t)row * DD;
  float v[4];
  float s = 0.f, s2 = 0.f;
#pragma unroll
  for (int i = 0; i < 4; ++i) {
    v[i] = bf2f(p[i * 64 + lane]);
    s += v[i]; s2 += v[i] * v[i];
  }
  for (int off = 32; off; off >>= 1) { s += __shfl_xor(s, off); s2 += __shfl_xor(s2, off); }
  float mean = s * (1.f / 256.f);
  float var  = s2 * (1.f / 256.f) - mean * mean;
  float inv  = rsqrtf(var + 1e-5f);
#pragma unroll
  for (int i = 0; i < 4; ++i) {
    int c = i * 64 + lane;
    p[c] = f2bf((v[i] - mean) * inv * g[c] + b[c]);
  }
}

__global__ __launch_bounds__(256) void k_final(const unsigned short* __restrict__ seqc,
                                               int n0, int cn,
                                               const float* __restrict__ g,
                                               const float* __restrict__ b,
                                               float* __restrict__ out) {
  int ln = blockIdx.x * 4 + (threadIdx.x >> 6);
  if (ln >= cn) return;
  int lane = threadIdx.x & 63;
  const unsigned short* p = seqc + (size_t)ln * 3 * DD;   // token 0 row
  float v[4];
  float s = 0.f, s2 = 0.f;
#pragma unroll
  for (int i = 0; i < 4; ++i) {
    v[i] = bf2f(p[i * 64 + lane]);
    s += v[i]; s2 += v[i] * v[i];
  }
  for (int off = 32; off; off >>= 1) { s += __shfl_xor(s, off); s2 += __shfl_xor(s2, off); }
  float mean = s * (1.f / 256.f);
  float var  = s2 * (1.f / 256.f) - mean * mean;
  float inv  = rsqrtf(var + 1e-5f);
#pragma unroll
  for (int i = 0; i < 4; ++i) {
    int c = i * 64 + lane;
    out[(size_t)(n0 + ln) * DD + c] = (v[i] - mean) * inv * g[c] + b[c];
  }
}

// ---------------- host ----------------

extern "C" void kernel_launch(void* const* d_in, const int* in_sizes, int n_in,
                              void* d_out, int out_size, void* d_ws, size_t ws_size,
                              hipStream_t stream) {
  const float* x       = (const float*)d_in[0];
  const int*   ei      = (const int*)d_in[1];
  const float* gat1_W  = (const float*)d_in[2];
  const float* gat1_b  = (const float*)d_in[3];
  const float* gat1_as = (const float*)d_in[4];
  const float* gat1_ad = (const float*)d_in[5];
  const float* gat2_W  = (const float*)d_in[6];
  const float* gat2_b  = (const float*)d_in[7];
  const float* gat2_as = (const float*)d_in[8];
  const float* gat2_ad = (const float*)d_in[9];
  const float* cls     = (const float*)d_in[10];
  const float* pos     = (const float*)d_in[11];
  const float* Wqkv    = (const float*)d_in[12];
  const float* bqkv    = (const float*)d_in[13];
  const float* Wo      = (const float*)d_in[14];
  const float* bo      = (const float*)d_in[15];
  const float* ln1_g   = (const float*)d_in[16];
  const float* ln1_b   = (const float*)d_in[17];
  const float* ln2_g   = (const float*)d_in[18];
  const float* ln2_b   = (const float*)d_in[19];
  const float* Wff1    = (const float*)d_in[20];
  const float* bff1    = (const float*)d_in[21];
  const float* Wff2    = (const float*)d_in[22];
  const float* bff2    = (const float*)d_in[23];
  const float* norm_g  = (const float*)d_in[24];
  const float* norm_b  = (const float*)d_in[25];
  float* out = (float*)d_out;

  char* ws = (char*)d_ws;
  size_t off = 0;
  auto alloc = [&](size_t bytes) -> void* {
    off = (off + 255) & ~(size_t)255;
    void* p = ws + off;
    off += bytes;
    return p;
  };

  unsigned short* wb_g1  = (unsigned short*)alloc(sizeof(unsigned short) * 256 * 128);
  unsigned short* wb_g2  = (unsigned short*)alloc(sizeof(unsigned short) * 256 * 256);
  unsigned short* wb_qkv = (unsigned short*)alloc(sizeof(unsigned short) * 2 * 768 * 256);
  unsigned short* wb_o   = (unsigned short*)alloc(sizeof(unsigned short) * 2 * 256 * 256);
  unsigned short* wb_f1  = (unsigned short*)alloc(sizeof(unsigned short) * 2 * 1024 * 256);
  unsigned short* wb_f2  = (unsigned short*)alloc(sizeof(unsigned short) * 2 * 256 * 1024);
  unsigned short* xb  = (unsigned short*)alloc(sizeof(unsigned short) * (size_t)NN * DIN);
  unsigned short* hb  = (unsigned short*)alloc(sizeof(unsigned short) * (size_t)NN * DD);
  unsigned short* x1b = (unsigned short*)alloc(sizeof(unsigned short) * (size_t)NN * DD);
  unsigned short* x2b = (unsigned short*)alloc(sizeof(unsigned short) * (size_t)NN * DD);
  float* hs  = (float*)alloc(sizeof(float) * NN);
  float* hd  = (float*)alloc(sizeof(float) * NN);
  int* deg   = (int*)alloc(sizeof(int) * NN);
  int* inc   = (int*)alloc(sizeof(int) * NN);
  int* cur   = (int*)alloc(sizeof(int) * NN);
  int* tsum  = (int*)alloc(sizeof(int) * 64);
  int* ssrc  = (int*)alloc(sizeof(int) * E2);

  // transformer chunking: keep per-chunk activations L3-resident (~154 MB @ 12500)
  size_t fixed = (off + 255) & ~(size_t)255;
  size_t rem = (ws_size > fixed + 4096) ? (ws_size - fixed - 4096) : 0;
  const size_t per_node = (size_t)3 * (256 + 768 + 1024) * 2;
  size_t cn_max = rem / per_node;
  if (cn_max < 1) cn_max = 1;
  if (cn_max > 12500) cn_max = 12500;
  int nc = (int)((NN + cn_max - 1) / cn_max);
  int cn = (NN + nc - 1) / nc;
  unsigned short* seqc = (unsigned short*)alloc(sizeof(unsigned short) * (size_t)3 * cn * 256);
  unsigned short* qkvb = (unsigned short*)alloc(sizeof(unsigned short) * (size_t)3 * cn * 768);
  unsigned short* ffb  = (unsigned short*)alloc(sizeof(unsigned short) * (size_t)3 * cn * 1024);

  // ---- casts ----
  auto cast = [&](const float* src, unsigned short* dst, int n) {
    k_cast<<<(n + 255) / 256, 256, 0, stream>>>(src, dst, n);
  };
  cast(gat1_W, wb_g1, 256 * 128);
  cast(gat2_W, wb_g2, 256 * 256);
  cast(Wqkv, wb_qkv, 2 * 768 * 256);
  cast(Wo, wb_o, 2 * 256 * 256);
  cast(Wff1, wb_f1, 2 * 1024 * 256);
  cast(Wff2, wb_f2, 2 * 256 * 1024);
  cast(x, xb, NN * DIN);

  // ---- CSR build ----
  hipMemsetAsync(deg, 0, sizeof(int) * NN, stream);
  hipMemsetAsync(cur, 0, sizeof(int) * NN, stream);
  k_deg<<<(E2 + 255) / 256, 256, 0, stream>>>(ei, deg);
  int nb = (NN + 1023) / 1024;
  k_scan_tile<<<nb, 1024, 0, stream>>>(deg, inc, tsum, NN);
  k_scan_sums<<<1, 64, 0, stream>>>(tsum, nb);
  k_scan_add<<<(NN + 255) / 256, 256, 0, stream>>>(inc, tsum, NN);
  k_scatter<<<(E2 + 255) / 256, 256, 0, stream>>>(ei, deg, inc, cur, ssrc);

  auto gemm = [&](const unsigned short* A, int lda, const unsigned short* B,
                  const float* bias, const unsigned short* R, int ldr,
                  unsigned short* C, int ldc, int M, int N, int K, int act) {
    dim3 grid(N / 128, (M + 127) / 128);
    k_gemm128<<<grid, 256, 0, stream>>>(A, lda, B, bias, R, ldr, C, ldc, M, N, K, act);
  };

  // ---- GAT layer 1: hb = xb @ W1^T (K=128) ----
  gemm(xb, DIN, wb_g1, nullptr, nullptr, 0, hb, DD, NN, DD, DIN, 0);
  k_dots<<<(NN + 3) / 4, 256, 0, stream>>>(hb, gat1_as, gat1_ad, hs, hd);
  k_gat<<<(NN + 3) / 4, 256, 0, stream>>>(hb, ssrc, deg, inc, hs, hd, gat1_b, x1b);

  // ---- GAT layer 2: hb = x1b @ W2^T (K=256) ----
  gemm(x1b, DD, wb_g2, nullptr, nullptr, 0, hb, DD, NN, DD, DD, 0);
  k_dots<<<(NN + 3) / 4, 256, 0, stream>>>(hb, gat2_as, gat2_ad, hs, hd);
  k_gat<<<(NN + 3) / 4, 256, 0, stream>>>(hb, ssrc, deg, inc, hs, hd, gat2_b, x2b);

  // ---- transformer (chunked; chunk activations stay L3-resident) ----
  for (int n0 = 0; n0 < NN; n0 += cn) {
    int c = NN - n0 < cn ? NN - n0 : cn;
    int Mch = 3 * c;
    k_seqbuild<<<(c * 3 * DD + 255) / 256, 256, 0, stream>>>(x1b, x2b, cls, pos, seqc, n0, c);
    for (int l = 0; l < 2; ++l) {
      gemm(seqc, DD, wb_qkv + (size_t)l * 768 * 256, bqkv + l * 768,
           nullptr, 0, qkvb, 768, Mch, 768, DD, 0);
      k_attn<<<c, 256, 0, stream>>>(qkvb);
      gemm(qkvb, 768, wb_o + (size_t)l * 256 * 256, bo + l * 256,
           seqc, DD, seqc, DD, Mch, DD, DD, 0);
      k_ln<<<(Mch + 3) / 4, 256, 0, stream>>>(seqc, Mch, ln1_g + l * 256, ln1_b + l * 256);
      gemm(seqc, DD, wb_f1 + (size_t)l * 1024 * 256, bff1 + l * 1024,
           nullptr, 0, ffb, 1024, Mch, 1024, DD, 1);
      gemm(ffb, 1024, wb_f2 + (size_t)l * 256 * 1024, bff2 + l * 256,
           seqc, DD, seqc, DD, Mch, DD, 1024, 0);
      k_ln<<<(Mch + 3) / 4, 256, 0, stream>>>(seqc, Mch, ln2_g + l * 256, ln2_b + l * 256);
    }
    k_final<<<(c + 3) / 4, 256, 0, stream>>>(seqc, n0, c, norm_g, norm_b, out);
  }
}

// Round 6
// 2540.068 us; speedup vs baseline: 1.8385x; 1.1447x over previous
//
#include <hip/hip_runtime.h>
#include <hip/hip_bf16.h>

#define NN  50000
#define EE  320000
#define E2  (EE + NN)
#define DIN 128
#define DD  256

typedef __attribute__((ext_vector_type(8))) short    bf16x8;
typedef __attribute__((ext_vector_type(4))) float    f32x4;

// ---------------- helpers ----------------

static __device__ __forceinline__ float bf2f(unsigned short u) {
  return __builtin_bit_cast(float, (unsigned)u << 16);
}

static __device__ __forceinline__ unsigned short f2bf(float f) {
  unsigned u = __builtin_bit_cast(unsigned, f);
  return (unsigned short)((u + 0x7fffu + ((u >> 16) & 1u)) >> 16);
}

static __device__ __forceinline__ void load_lds16(const void* g, void* l) {
  __builtin_amdgcn_global_load_lds(
      (const __attribute__((address_space(1))) void*)g,
      (__attribute__((address_space(3))) void*)l, 16, 0, 0);
}

// ---------------- weight/activation cast fp32 -> bf16 ----------------

__global__ void k_cast(const float* __restrict__ in, unsigned short* __restrict__ out, int n) {
  int i = blockIdx.x * blockDim.x + threadIdx.x;
  if (i >= n) return;
  out[i] = f2bf(in[i]);
}

// ---------------- CSR build ----------------

__global__ void k_deg(const int* __restrict__ ei, int* __restrict__ deg) {
  int i = blockIdx.x * blockDim.x + threadIdx.x;
  if (i >= E2) return;
  int dst = (i < EE) ? ei[EE + i] : (i - EE);
  atomicAdd(&deg[dst], 1);
}

__global__ __launch_bounds__(1024) void k_scan_tile(const int* __restrict__ in,
                                                    int* __restrict__ out,
                                                    int* __restrict__ tsum, int n) {
  __shared__ int sm[1024];
  int tid = threadIdx.x;
  int g = blockIdx.x * 1024 + tid;
  sm[tid] = (g < n) ? in[g] : 0;
  __syncthreads();
  for (int off = 1; off < 1024; off <<= 1) {
    int t = (tid >= off) ? sm[tid - off] : 0;
    __syncthreads();
    sm[tid] += t;
    __syncthreads();
  }
  if (g < n) out[g] = sm[tid];
  if (tid == 1023) tsum[blockIdx.x] = sm[1023];
}

__global__ void k_scan_sums(int* __restrict__ tsum, int nb) {
  int tid = threadIdx.x;           // single wave of 64, nb <= 64
  int v = (tid < nb) ? tsum[tid] : 0;
  for (int off = 1; off < 64; off <<= 1) {
    int t = __shfl_up(v, off);
    if (tid >= off) v += t;
  }
  if (tid < nb) tsum[tid] = v;
}

__global__ void k_scan_add(int* __restrict__ out, const int* __restrict__ tsum, int n) {
  int g = blockIdx.x * blockDim.x + threadIdx.x;
  if (g >= n || g < 1024) return;
  out[g] += tsum[(g >> 10) - 1];
}

__global__ void k_scatter(const int* __restrict__ ei, const int* __restrict__ deg,
                          const int* __restrict__ inc, int* __restrict__ cur,
                          int* __restrict__ ssrc) {
  int i = blockIdx.x * blockDim.x + threadIdx.x;
  if (i >= E2) return;
  int src, dst;
  if (i < EE) { src = ei[i]; dst = ei[EE + i]; } else { src = dst = i - EE; }
  int pos = atomicAdd(&cur[dst], 1);
  ssrc[inc[dst] - deg[dst] + pos] = src;
}

// ---------------- GAT pieces (h in bf16) ----------------

__global__ __launch_bounds__(256) void k_dots(const unsigned short* __restrict__ hb,
                                              const float* __restrict__ asrc,
                                              const float* __restrict__ adst,
                                              float* __restrict__ hs, float* __restrict__ hd) {
  int node = blockIdx.x * 4 + (threadIdx.x >> 6);
  if (node >= NN) return;
  int lane = threadIdx.x & 63;
  ushort4 hv = *reinterpret_cast<const ushort4*>(hb + (size_t)node * DD + lane * 4);
  float v0 = bf2f(hv.x), v1 = bf2f(hv.y), v2 = bf2f(hv.z), v3 = bf2f(hv.w);
  const float* as = asrc + lane * 4;
  const float* ad = adst + lane * 4;
  float s1 = v0 * as[0] + v1 * as[1] + v2 * as[2] + v3 * as[3];
  float s2 = v0 * ad[0] + v1 * ad[1] + v2 * ad[2] + v3 * ad[3];
  for (int off = 32; off; off >>= 1) {
    s1 += __shfl_xor(s1, off);
    s2 += __shfl_xor(s2, off);
  }
  if (lane == 0) { hs[node] = s1; hd[node] = s2; }
}

// Fused edge-softmax + aggregation: one wave per dst node.
__global__ __launch_bounds__(256) void k_gat(const unsigned short* __restrict__ hb,
                                             const int* __restrict__ ssrc,
                                             const int* __restrict__ deg,
                                             const int* __restrict__ inc,
                                             const float* __restrict__ hs,
                                             const float* __restrict__ hd,
                                             const float* __restrict__ bias,
                                             unsigned short* __restrict__ out) {
  __shared__ float sE[4][256];
  __shared__ int   sI[4][256];
  int w = threadIdx.x >> 6;
  int d = blockIdx.x * 4 + w;
  if (d >= NN) return;
  int lane = threadIdx.x & 63;
  int end = inc[d], cnt = deg[d], base = end - cnt;
  if (cnt > 256) cnt = 256;
  float hdd = hd[d];

  float m = -1e30f;
  for (int i0 = 0; i0 < cnt; i0 += 64) {
    int i = i0 + lane;
    float sc = -1e30f;
    if (i < cnt) {
      int s = ssrc[base + i];
      float v = hs[s] + hdd;
      sc = (v < 0.f) ? 0.2f * v : v;
      sI[w][i] = s;
      sE[w][i] = sc;
    }
    float mm = sc;
    for (int o = 32; o; o >>= 1) mm = fmaxf(mm, __shfl_xor(mm, o));
    m = fmaxf(m, mm);
  }
  float sum = 0.f;
  for (int i0 = 0; i0 < cnt; i0 += 64) {
    int i = i0 + lane;
    float e = 0.f;
    if (i < cnt) {
      e = __expf(sE[w][i] - m);
      sE[w][i] = e;
    }
    for (int o = 32; o; o >>= 1) e += __shfl_xor(e, o);
    sum += e;
  }
  float inv = 1.f / sum;

  float a0 = 0.f, a1 = 0.f, a2 = 0.f, a3 = 0.f;
  for (int i = 0; i < cnt; ++i) {
    float a = sE[w][i];
    int s = sI[w][i];
    ushort4 hv = *reinterpret_cast<const ushort4*>(hb + (size_t)s * DD + lane * 4);
    a0 += a * bf2f(hv.x);
    a1 += a * bf2f(hv.y);
    a2 += a * bf2f(hv.z);
    a3 += a * bf2f(hv.w);
  }
  const float* bp = bias + lane * 4;
  float r0 = a0 * inv + bp[0], r1 = a1 * inv + bp[1];
  float r2 = a2 * inv + bp[2], r3 = a3 * inv + bp[3];
  ushort4 o;
  o.x = f2bf(r0 > 0.f ? r0 : 0.f);
  o.y = f2bf(r1 > 0.f ? r1 : 0.f);
  o.z = f2bf(r2 > 0.f ? r2 : 0.f);
  o.w = f2bf(r3 > 0.f ? r3 : 0.f);
  *reinterpret_cast<ushort4*>(out + (size_t)d * DD + lane * 4) = o;
}

// ---------------- LDS-staged bf16 MFMA GEMM, XCD-swizzled grid ----------------
// C = act(A @ B^T + bias);  A bf16 [M x K] lda, B bf16 [N x K], C bf16 [M x ldc].
// 128x128 tile, BK=32, 4 waves. Grid: (N/128, ceil8(M/128)); the linear block id
// is remapped so all n-columns of one m-tile run on the SAME XCD (id%8) -> the
// A-tile is fetched from HBM once per m-tile and L2-reused across n-columns.

__global__ __launch_bounds__(256) void k_gemm128(
    const unsigned short* __restrict__ A, int lda,
    const unsigned short* __restrict__ B,
    const float* __restrict__ bias,
    unsigned short* __restrict__ C, int ldc,
    int M, int N, int K, int act) {
  __shared__ unsigned short As[128 * 32];
  __shared__ unsigned short Bs[128 * 32];

  const int id  = blockIdx.y * gridDim.x + blockIdx.x;
  const int nn  = gridDim.x;
  const int sid = id >> 3;
  const int jn  = sid % nn;
  const int im  = (id & 7) + ((sid / nn) << 3);
  if (im >= ((M + 127) >> 7)) return;   // padded m-tiles exit
  const int m0 = im * 128;
  const int n0 = jn * 128;

  const int tid    = threadIdx.x;
  const int lane   = tid & 63;
  const int w      = tid >> 6;
  const int m_lane = lane & 15;
  const int quad   = lane >> 4;
  const int wm     = (w >> 1) * 64;
  const int wn     = (w & 1) * 64;

  const int idx0 = tid, idx1 = 256 + tid;
  int rowA0 = m0 + (idx0 >> 2); if (rowA0 >= M) rowA0 = M - 1;
  int rowA1 = m0 + (idx1 >> 2); if (rowA1 >= M) rowA1 = M - 1;
  const unsigned short* gA0 = A + (size_t)rowA0 * lda + (idx0 & 3) * 8;
  const unsigned short* gA1 = A + (size_t)rowA1 * lda + (idx1 & 3) * 8;
  const unsigned short* gB0 = B + (size_t)(n0 + (idx0 >> 2)) * K + (idx0 & 3) * 8;
  const unsigned short* gB1 = B + (size_t)(n0 + (idx1 >> 2)) * K + (idx1 & 3) * 8;

  unsigned short* lA0 = As + (size_t)(w * 64) * 8;
  unsigned short* lA1 = As + (size_t)(256 + w * 64) * 8;
  unsigned short* lB0 = Bs + (size_t)(w * 64) * 8;
  unsigned short* lB1 = Bs + (size_t)(256 + w * 64) * 8;

  f32x4 acc[4][4] = {};

  for (int k0 = 0; k0 < K; k0 += 32) {
    load_lds16(gA0, lA0);
    load_lds16(gA1, lA1);
    load_lds16(gB0, lB0);
    load_lds16(gB1, lB1);
    gA0 += 32; gA1 += 32; gB0 += 32; gB1 += 32;
    __syncthreads();

    bf16x8 af[4], bg[4];
#pragma unroll
    for (int i = 0; i < 4; ++i)
      af[i] = *reinterpret_cast<const bf16x8*>(As + (wm + i * 16 + m_lane) * 32 + quad * 8);
#pragma unroll
    for (int j = 0; j < 4; ++j)
      bg[j] = *reinterpret_cast<const bf16x8*>(Bs + (wn + j * 16 + m_lane) * 32 + quad * 8);
#pragma unroll
    for (int i = 0; i < 4; ++i)
#pragma unroll
      for (int j = 0; j < 4; ++j)
        acc[i][j] = __builtin_amdgcn_mfma_f32_16x16x32_bf16(af[i], bg[j], acc[i][j], 0, 0, 0);
    __syncthreads();
  }

#pragma unroll
  for (int i = 0; i < 4; ++i) {
#pragma unroll
    for (int j = 0; j < 4; ++j) {
      int col = n0 + wn + j * 16 + m_lane;
      float bv = bias ? bias[col] : 0.f;
#pragma unroll
      for (int r = 0; r < 4; ++r) {
        int row = m0 + wm + i * 16 + quad * 4 + r;
        if (row < M) {
          float v = acc[i][j][r] + bv;
          if (act) v = v > 0.f ? v : 0.f;
          C[(size_t)row * ldc + col] = f2bf(v);
        }
      }
    }
  }
}

// ---------------- fused GEMM(+bias+residual)+LayerNorm, N=256 exactly ----------------
// C = LN(A @ B^T + bias + R) * g + b.  64x256 tile -> each block owns full rows;
// LN stats reduce in-register (sum over 16 j-frags + shuffles across 16-lane group).

__global__ __launch_bounds__(256) void k_gemm_ln(
    const unsigned short* __restrict__ A, int lda,
    const unsigned short* __restrict__ B,           // [256 x K]
    const float* __restrict__ bias,                 // [256]
    const unsigned short* __restrict__ R, int ldr,  // residual bf16 [M x ldr]
    const float* __restrict__ gam, const float* __restrict__ bet,
    unsigned short* __restrict__ C, int ldc,
    int M, int K) {
  __shared__ unsigned short As[64 * 32];    // 4 KB
  __shared__ unsigned short Bs[256 * 32];   // 16 KB

  const int tid    = threadIdx.x;
  const int lane   = tid & 63;
  const int w      = tid >> 6;
  const int m_lane = lane & 15;
  const int quad   = lane >> 4;
  const int m0     = blockIdx.x * 64;

  int rowA = m0 + (tid >> 2); if (rowA >= M) rowA = M - 1;
  const unsigned short* gA = A + (size_t)rowA * lda + (tid & 3) * 8;
  const unsigned short* gB0 = B + (size_t)(0   + (tid >> 2)) * K + (tid & 3) * 8;
  const unsigned short* gB1 = B + (size_t)(64  + (tid >> 2)) * K + (tid & 3) * 8;
  const unsigned short* gB2 = B + (size_t)(128 + (tid >> 2)) * K + (tid & 3) * 8;
  const unsigned short* gB3 = B + (size_t)(192 + (tid >> 2)) * K + (tid & 3) * 8;

  unsigned short* lA  = As + (size_t)w * 512;
  unsigned short* lB0 = Bs + (size_t)(0 * 256 + w * 64) * 8;
  unsigned short* lB1 = Bs + (size_t)(1 * 256 + w * 64) * 8;
  unsigned short* lB2 = Bs + (size_t)(2 * 256 + w * 64) * 8;
  unsigned short* lB3 = Bs + (size_t)(3 * 256 + w * 64) * 8;

  f32x4 acc[16] = {};

  for (int k0 = 0; k0 < K; k0 += 32) {
    load_lds16(gA,  lA);
    load_lds16(gB0, lB0);
    load_lds16(gB1, lB1);
    load_lds16(gB2, lB2);
    load_lds16(gB3, lB3);
    gA += 32; gB0 += 32; gB1 += 32; gB2 += 32; gB3 += 32;
    __syncthreads();

    bf16x8 af = *reinterpret_cast<const bf16x8*>(As + (w * 16 + m_lane) * 32 + quad * 8);
#pragma unroll
    for (int j = 0; j < 16; ++j) {
      bf16x8 bg = *reinterpret_cast<const bf16x8*>(Bs + (j * 16 + m_lane) * 32 + quad * 8);
      acc[j] = __builtin_amdgcn_mfma_f32_16x16x32_bf16(af, bg, acc[j], 0, 0, 0);
    }
    __syncthreads();
  }

  // epilogue: bias + residual, then LN per row, scaled write
#pragma unroll
  for (int r = 0; r < 4; ++r) {
    int row = m0 + w * 16 + quad * 4 + r;
    int rr = row < M ? row : M - 1;
    float v[16];
    float s = 0.f, s2 = 0.f;
#pragma unroll
    for (int j = 0; j < 16; ++j) {
      int col = j * 16 + m_lane;
      float t = acc[j][r] + bias[col] + bf2f(R[(size_t)rr * ldr + col]);
      v[j] = t;
      s += t; s2 += t * t;
    }
#pragma unroll
    for (int o = 1; o < 16; o <<= 1) {
      s  += __shfl_xor(s, o);
      s2 += __shfl_xor(s2, o);
    }
    float mean = s * (1.f / 256.f);
    float var  = s2 * (1.f / 256.f) - mean * mean;
    float inv  = rsqrtf(var + 1e-5f);
    if (row < M) {
#pragma unroll
      for (int j = 0; j < 16; ++j) {
        int col = j * 16 + m_lane;
        C[(size_t)row * ldc + col] = f2bf((v[j] - mean) * inv * gam[col] + bet[col]);
      }
    }
  }
}

// ---------------- transformer pieces (bf16 activations, dense layouts) ----------------

__global__ void k_seqbuild(const unsigned short* __restrict__ x1,
                           const unsigned short* __restrict__ x2,
                           const float* __restrict__ cls, const float* __restrict__ pos,
                           unsigned short* __restrict__ seqc, int n0, int cn) {
  int idx = blockIdx.x * blockDim.x + threadIdx.x;
  int total = cn * 3 * DD;
  if (idx >= total) return;
  int c = idx & (DD - 1);
  int r = idx >> 8;
  int t = r % 3, ln = r / 3;
  int n = n0 + ln;
  float v;
  if (t == 0)      v = cls[c];
  else if (t == 1) v = bf2f(x1[(size_t)n * DD + c]);
  else             v = bf2f(x2[(size_t)n * DD + c]);
  seqc[idx] = f2bf(v + pos[t * DD + c]);
}

// qkv: [3 rows x 768] per node; attention output overwrites the q slot in place.
__global__ __launch_bounds__(256) void k_attn(unsigned short* __restrict__ qkvb) {
  __shared__ float qkv[3][768];
  __shared__ float lg[4][3][3];
  __shared__ float aw[4][3][3];
  int tid = threadIdx.x;
  size_t r0 = (size_t)blockIdx.x * 3;
  for (int i = tid; i < 3 * 768; i += 256) {
    int r = i / 768, c = i % 768;
    qkv[r][c] = bf2f(qkvb[(r0 + r) * 768 + c]);
  }
  __syncthreads();
  int h = tid >> 6, lane = tid & 63;
#pragma unroll
  for (int ti = 0; ti < 3; ++ti)
#pragma unroll
    for (int j = 0; j < 3; ++j) {
      float p = qkv[ti][h * 64 + lane] * qkv[j][256 + h * 64 + lane];
      for (int off = 32; off; off >>= 1) p += __shfl_xor(p, off);
      if (lane == 0) lg[h][ti][j] = p * 0.125f;
    }
  __syncthreads();
  if (lane < 3) {
    int ti = lane;
    float l0 = lg[h][ti][0], l1 = lg[h][ti][1], l2 = lg[h][ti][2];
    float m = fmaxf(l0, fmaxf(l1, l2));
    float e0 = __expf(l0 - m), e1 = __expf(l1 - m), e2 = __expf(l2 - m);
    float inv = 1.f / (e0 + e1 + e2);
    aw[h][ti][0] = e0 * inv; aw[h][ti][1] = e1 * inv; aw[h][ti][2] = e2 * inv;
  }
  __syncthreads();
  int c = tid;
#pragma unroll
  for (int ti = 0; ti < 3; ++ti) {
    float o = aw[h][ti][0] * qkv[0][512 + c] +
              aw[h][ti][1] * qkv[1][512 + c] +
              aw[h][ti][2] * qkv[2][512 + c];
    qkvb[(r0 + ti) * 768 + c] = f2bf(o);   // overwrite q slot
  }
}

__global__ __launch_bounds__(256) void k_final(const unsigned short* __restrict__ seqc,
                                               int n0, int cn,
                                               const float* __restrict__ g,
                                               const float* __restrict__ b,
                                               float* __restrict__ out) {
  int ln = blockIdx.x * 4 + (threadIdx.x >> 6);
  if (ln >= cn) return;
  int lane = threadIdx.x & 63;
  const unsigned short* p = seqc + (size_t)ln * 3 * DD;   // token 0 row
  float v[4];
  float s = 0.f, s2 = 0.f;
#pragma unroll
  for (int i = 0; i < 4; ++i) {
    v[i] = bf2f(p[i * 64 + lane]);
    s += v[i]; s2 += v[i] * v[i];
  }
  for (int off = 32; off; off >>= 1) { s += __shfl_xor(s, off); s2 += __shfl_xor(s2, off); }
  float mean = s * (1.f / 256.f);
  float var  = s2 * (1.f / 256.f) - mean * mean;
  float inv  = rsqrtf(var + 1e-5f);
#pragma unroll
  for (int i = 0; i < 4; ++i) {
    int c = i * 64 + lane;
    out[(size_t)(n0 + ln) * DD + c] = (v[i] - mean) * inv * g[c] + b[c];
  }
}

// ---------------- host ----------------

extern "C" void kernel_launch(void* const* d_in, const int* in_sizes, int n_in,
                              void* d_out, int out_size, void* d_ws, size_t ws_size,
                              hipStream_t stream) {
  const float* x       = (const float*)d_in[0];
  const int*   ei      = (const int*)d_in[1];
  const float* gat1_W  = (const float*)d_in[2];
  const float* gat1_b  = (const float*)d_in[3];
  const float* gat1_as = (const float*)d_in[4];
  const float* gat1_ad = (const float*)d_in[5];
  const float* gat2_W  = (const float*)d_in[6];
  const float* gat2_b  = (const float*)d_in[7];
  const float* gat2_as = (const float*)d_in[8];
  const float* gat2_ad = (const float*)d_in[9];
  const float* cls     = (const float*)d_in[10];
  const float* pos     = (const float*)d_in[11];
  const float* Wqkv    = (const float*)d_in[12];
  const float* bqkv    = (const float*)d_in[13];
  const float* Wo      = (const float*)d_in[14];
  const float* bo      = (const float*)d_in[15];
  const float* ln1_g   = (const float*)d_in[16];
  const float* ln1_b   = (const float*)d_in[17];
  const float* ln2_g   = (const float*)d_in[18];
  const float* ln2_b   = (const float*)d_in[19];
  const float* Wff1    = (const float*)d_in[20];
  const float* bff1    = (const float*)d_in[21];
  const float* Wff2    = (const float*)d_in[22];
  const float* bff2    = (const float*)d_in[23];
  const float* norm_g  = (const float*)d_in[24];
  const float* norm_b  = (const float*)d_in[25];
  float* out = (float*)d_out;

  char* ws = (char*)d_ws;
  size_t off = 0;
  auto alloc = [&](size_t bytes) -> void* {
    off = (off + 255) & ~(size_t)255;
    void* p = ws + off;
    off += bytes;
    return p;
  };

  unsigned short* wb_g1  = (unsigned short*)alloc(sizeof(unsigned short) * 256 * 128);
  unsigned short* wb_g2  = (unsigned short*)alloc(sizeof(unsigned short) * 256 * 256);
  unsigned short* wb_qkv = (unsigned short*)alloc(sizeof(unsigned short) * 2 * 768 * 256);
  unsigned short* wb_o   = (unsigned short*)alloc(sizeof(unsigned short) * 2 * 256 * 256);
  unsigned short* wb_f1  = (unsigned short*)alloc(sizeof(unsigned short) * 2 * 1024 * 256);
  unsigned short* wb_f2  = (unsigned short*)alloc(sizeof(unsigned short) * 2 * 256 * 1024);
  unsigned short* xb  = (unsigned short*)alloc(sizeof(unsigned short) * (size_t)NN * DIN);
  unsigned short* hb  = (unsigned short*)alloc(sizeof(unsigned short) * (size_t)NN * DD);
  unsigned short* x1b = (unsigned short*)alloc(sizeof(unsigned short) * (size_t)NN * DD);
  unsigned short* x2b = (unsigned short*)alloc(sizeof(unsigned short) * (size_t)NN * DD);
  float* hs  = (float*)alloc(sizeof(float) * NN);
  float* hd  = (float*)alloc(sizeof(float) * NN);
  int* deg   = (int*)alloc(sizeof(int) * NN);
  int* inc   = (int*)alloc(sizeof(int) * NN);
  int* cur   = (int*)alloc(sizeof(int) * NN);
  int* tsum  = (int*)alloc(sizeof(int) * 64);
  int* ssrc  = (int*)alloc(sizeof(int) * E2);

  // transformer chunking (L3 residency of per-chunk activations)
  size_t fixed = (off + 255) & ~(size_t)255;
  size_t rem = (ws_size > fixed + 4096) ? (ws_size - fixed - 4096) : 0;
  const size_t per_node = (size_t)3 * (256 + 768 + 1024) * 2;
  size_t cn_max = rem / per_node;
  if (cn_max < 1) cn_max = 1;
  if (cn_max > 12500) cn_max = 12500;
  int nc = (int)((NN + cn_max - 1) / cn_max);
  int cn = (NN + nc - 1) / nc;
  unsigned short* seqc = (unsigned short*)alloc(sizeof(unsigned short) * (size_t)3 * cn * 256);
  unsigned short* qkvb = (unsigned short*)alloc(sizeof(unsigned short) * (size_t)3 * cn * 768);
  unsigned short* ffb  = (unsigned short*)alloc(sizeof(unsigned short) * (size_t)3 * cn * 1024);

  // ---- casts ----
  auto cast = [&](const float* src, unsigned short* dst, int n) {
    k_cast<<<(n + 255) / 256, 256, 0, stream>>>(src, dst, n);
  };
  cast(gat1_W, wb_g1, 256 * 128);
  cast(gat2_W, wb_g2, 256 * 256);
  cast(Wqkv, wb_qkv, 2 * 768 * 256);
  cast(Wo, wb_o, 2 * 256 * 256);
  cast(Wff1, wb_f1, 2 * 1024 * 256);
  cast(Wff2, wb_f2, 2 * 256 * 1024);
  cast(x, xb, NN * DIN);

  // ---- CSR build ----
  hipMemsetAsync(deg, 0, sizeof(int) * NN, stream);
  hipMemsetAsync(cur, 0, sizeof(int) * NN, stream);
  k_deg<<<(E2 + 255) / 256, 256, 0, stream>>>(ei, deg);
  int nb = (NN + 1023) / 1024;
  k_scan_tile<<<nb, 1024, 0, stream>>>(deg, inc, tsum, NN);
  k_scan_sums<<<1, 64, 0, stream>>>(tsum, nb);
  k_scan_add<<<(NN + 255) / 256, 256, 0, stream>>>(inc, tsum, NN);
  k_scatter<<<(E2 + 255) / 256, 256, 0, stream>>>(ei, deg, inc, cur, ssrc);

  auto gemm = [&](const unsigned short* A, int lda, const unsigned short* B,
                  const float* bias, unsigned short* C, int ldc,
                  int M, int N, int K, int act) {
    int nm = (M + 127) / 128;
    int nmp = (nm + 7) & ~7;
    dim3 grid(N / 128, nmp);
    k_gemm128<<<grid, 256, 0, stream>>>(A, lda, B, bias, C, ldc, M, N, K, act);
  };

  // ---- GAT layer 1: hb = xb @ W1^T (K=128) ----
  gemm(xb, DIN, wb_g1, nullptr, hb, DD, NN, DD, DIN, 0);
  k_dots<<<(NN + 3) / 4, 256, 0, stream>>>(hb, gat1_as, gat1_ad, hs, hd);
  k_gat<<<(NN + 3) / 4, 256, 0, stream>>>(hb, ssrc, deg, inc, hs, hd, gat1_b, x1b);

  // ---- GAT layer 2: hb = x1b @ W2^T (K=256) ----
  gemm(x1b, DD, wb_g2, nullptr, hb, DD, NN, DD, DD, 0);
  k_dots<<<(NN + 3) / 4, 256, 0, stream>>>(hb, gat2_as, gat2_ad, hs, hd);
  k_gat<<<(NN + 3) / 4, 256, 0, stream>>>(hb, ssrc, deg, inc, hs, hd, gat2_b, x2b);

  // ---- transformer (chunked) ----
  for (int n0 = 0; n0 < NN; n0 += cn) {
    int c = NN - n0 < cn ? NN - n0 : cn;
    int Mch = 3 * c;
    int mblk64 = (Mch + 63) / 64;
    k_seqbuild<<<(c * 3 * DD + 255) / 256, 256, 0, stream>>>(x1b, x2b, cls, pos, seqc, n0, c);
    for (int l = 0; l < 2; ++l) {
      // qkv: N=768, K=256
      gemm(seqc, DD, wb_qkv + (size_t)l * 768 * 256, bqkv + l * 768,
           qkvb, 768, Mch, 768, DD, 0);
      k_attn<<<c, 256, 0, stream>>>(qkvb);
      // o-proj + residual + ln1 fused (K=256)
      k_gemm_ln<<<mblk64, 256, 0, stream>>>(
          qkvb, 768, wb_o + (size_t)l * 256 * 256, bo + l * 256,
          seqc, DD, ln1_g + l * 256, ln1_b + l * 256, seqc, DD, Mch, DD);
      // ff1: N=1024, K=256, relu
      gemm(seqc, DD, wb_f1 + (size_t)l * 1024 * 256, bff1 + l * 1024,
           ffb, 1024, Mch, 1024, DD, 1);
      // ff2 + residual + ln2 fused (K=1024)
      k_gemm_ln<<<mblk64, 256, 0, stream>>>(
          ffb, 1024, wb_f2 + (size_t)l * 256 * 1024, bff2 + l * 256,
          seqc, DD, ln2_g + l * 256, ln2_b + l * 256, seqc, DD, Mch, 1024);
    }
    k_final<<<(c + 3) / 4, 256, 0, stream>>>(seqc, n0, c, norm_g, norm_b, out);
  }
}

// Round 7
// 2537.575 us; speedup vs baseline: 1.8403x; 1.0010x over previous
//
#include <hip/hip_runtime.h>
#include <hip/hip_bf16.h>

#define NN  50000
#define EE  320000
#define E2  (EE + NN)
#define DIN 128
#define DD  256

typedef __attribute__((ext_vector_type(8))) short    bf16x8;
typedef __attribute__((ext_vector_type(4))) float    f32x4;

// ---------------- helpers ----------------

static __device__ __forceinline__ float bf2f(unsigned short u) {
  return __builtin_bit_cast(float, (unsigned)u << 16);
}

static __device__ __forceinline__ unsigned short f2bf(float f) {
  unsigned u = __builtin_bit_cast(unsigned, f);
  return (unsigned short)((u + 0x7fffu + ((u >> 16) & 1u)) >> 16);
}

static __device__ __forceinline__ void load_lds16(const void* g, void* l) {
  __builtin_amdgcn_global_load_lds(
      (const __attribute__((address_space(1))) void*)g,
      (__attribute__((address_space(3))) void*)l, 16, 0, 0);
}

// ---------------- weight/activation cast fp32 -> bf16 ----------------

__global__ void k_cast(const float* __restrict__ in, unsigned short* __restrict__ out, int n) {
  int i = blockIdx.x * blockDim.x + threadIdx.x;
  if (i >= n) return;
  out[i] = f2bf(in[i]);
}

// ---------------- CSR build ----------------

__global__ void k_deg(const int* __restrict__ ei, int* __restrict__ deg) {
  int i = blockIdx.x * blockDim.x + threadIdx.x;
  if (i >= E2) return;
  int dst = (i < EE) ? ei[EE + i] : (i - EE);
  atomicAdd(&deg[dst], 1);
}

__global__ __launch_bounds__(1024) void k_scan_tile(const int* __restrict__ in,
                                                    int* __restrict__ out,
                                                    int* __restrict__ tsum, int n) {
  __shared__ int sm[1024];
  int tid = threadIdx.x;
  int g = blockIdx.x * 1024 + tid;
  sm[tid] = (g < n) ? in[g] : 0;
  __syncthreads();
  for (int off = 1; off < 1024; off <<= 1) {
    int t = (tid >= off) ? sm[tid - off] : 0;
    __syncthreads();
    sm[tid] += t;
    __syncthreads();
  }
  if (g < n) out[g] = sm[tid];
  if (tid == 1023) tsum[blockIdx.x] = sm[1023];
}

__global__ void k_scan_sums(int* __restrict__ tsum, int nb) {
  int tid = threadIdx.x;           // single wave of 64, nb <= 64
  int v = (tid < nb) ? tsum[tid] : 0;
  for (int off = 1; off < 64; off <<= 1) {
    int t = __shfl_up(v, off);
    if (tid >= off) v += t;
  }
  if (tid < nb) tsum[tid] = v;
}

__global__ void k_scan_add(int* __restrict__ out, const int* __restrict__ tsum, int n) {
  int g = blockIdx.x * blockDim.x + threadIdx.x;
  if (g >= n || g < 1024) return;
  out[g] += tsum[(g >> 10) - 1];
}

__global__ void k_scatter(const int* __restrict__ ei, const int* __restrict__ deg,
                          const int* __restrict__ inc, int* __restrict__ cur,
                          int* __restrict__ ssrc) {
  int i = blockIdx.x * blockDim.x + threadIdx.x;
  if (i >= E2) return;
  int src, dst;
  if (i < EE) { src = ei[i]; dst = ei[EE + i]; } else { src = dst = i - EE; }
  int pos = atomicAdd(&cur[dst], 1);
  ssrc[inc[dst] - deg[dst] + pos] = src;
}

// ---------------- GAT pieces (h in bf16) ----------------

__global__ __launch_bounds__(256) void k_dots(const unsigned short* __restrict__ hb,
                                              const float* __restrict__ asrc,
                                              const float* __restrict__ adst,
                                              float* __restrict__ hs, float* __restrict__ hd) {
  int node = blockIdx.x * 4 + (threadIdx.x >> 6);
  if (node >= NN) return;
  int lane = threadIdx.x & 63;
  ushort4 hv = *reinterpret_cast<const ushort4*>(hb + (size_t)node * DD + lane * 4);
  float v0 = bf2f(hv.x), v1 = bf2f(hv.y), v2 = bf2f(hv.z), v3 = bf2f(hv.w);
  const float* as = asrc + lane * 4;
  const float* ad = adst + lane * 4;
  float s1 = v0 * as[0] + v1 * as[1] + v2 * as[2] + v3 * as[3];
  float s2 = v0 * ad[0] + v1 * ad[1] + v2 * ad[2] + v3 * ad[3];
  for (int off = 32; off; off >>= 1) {
    s1 += __shfl_xor(s1, off);
    s2 += __shfl_xor(s2, off);
  }
  if (lane == 0) { hs[node] = s1; hd[node] = s2; }
}

// Fused edge-softmax + aggregation: one wave per dst node.
__global__ __launch_bounds__(256) void k_gat(const unsigned short* __restrict__ hb,
                                             const int* __restrict__ ssrc,
                                             const int* __restrict__ deg,
                                             const int* __restrict__ inc,
                                             const float* __restrict__ hs,
                                             const float* __restrict__ hd,
                                             const float* __restrict__ bias,
                                             unsigned short* __restrict__ out) {
  __shared__ float sE[4][256];
  __shared__ int   sI[4][256];
  int w = threadIdx.x >> 6;
  int d = blockIdx.x * 4 + w;
  if (d >= NN) return;
  int lane = threadIdx.x & 63;
  int end = inc[d], cnt = deg[d], base = end - cnt;
  if (cnt > 256) cnt = 256;
  float hdd = hd[d];

  float m = -1e30f;
  for (int i0 = 0; i0 < cnt; i0 += 64) {
    int i = i0 + lane;
    float sc = -1e30f;
    if (i < cnt) {
      int s = ssrc[base + i];
      float v = hs[s] + hdd;
      sc = (v < 0.f) ? 0.2f * v : v;
      sI[w][i] = s;
      sE[w][i] = sc;
    }
    float mm = sc;
    for (int o = 32; o; o >>= 1) mm = fmaxf(mm, __shfl_xor(mm, o));
    m = fmaxf(m, mm);
  }
  float sum = 0.f;
  for (int i0 = 0; i0 < cnt; i0 += 64) {
    int i = i0 + lane;
    float e = 0.f;
    if (i < cnt) {
      e = __expf(sE[w][i] - m);
      sE[w][i] = e;
    }
    for (int o = 32; o; o >>= 1) e += __shfl_xor(e, o);
    sum += e;
  }
  float inv = 1.f / sum;

  float a0 = 0.f, a1 = 0.f, a2 = 0.f, a3 = 0.f;
  for (int i = 0; i < cnt; ++i) {
    float a = sE[w][i];
    int s = sI[w][i];
    ushort4 hv = *reinterpret_cast<const ushort4*>(hb + (size_t)s * DD + lane * 4);
    a0 += a * bf2f(hv.x);
    a1 += a * bf2f(hv.y);
    a2 += a * bf2f(hv.z);
    a3 += a * bf2f(hv.w);
  }
  const float* bp = bias + lane * 4;
  float r0 = a0 * inv + bp[0], r1 = a1 * inv + bp[1];
  float r2 = a2 * inv + bp[2], r3 = a3 * inv + bp[3];
  ushort4 o;
  o.x = f2bf(r0 > 0.f ? r0 : 0.f);
  o.y = f2bf(r1 > 0.f ? r1 : 0.f);
  o.z = f2bf(r2 > 0.f ? r2 : 0.f);
  o.w = f2bf(r3 > 0.f ? r3 : 0.f);
  *reinterpret_cast<ushort4*>(out + (size_t)d * DD + lane * 4) = o;
}

// LDS k-chunk swizzle (bank-conflict-free fragment reads):
// LDS slot (row, c) holds global k-chunk  c ^ ((row>>1)&3).
// Staging slot idx: row=idx>>2, c=idx&3 -> source chunk = (idx&3)^((idx>>3)&3).
// Fragment read of logical chunk q at row (16-aligned base + m_lane):
//   position = q ^ ((m_lane>>1)&3).

// ---------------- LDS-staged bf16 MFMA GEMM, XCD-swizzled grid ----------------
// C = act(A @ B^T + bias);  A bf16 [M x K] lda, B bf16 [N x K], C bf16 [M x ldc].
// 128x128 tile, BK=32, 4 waves.

__global__ __launch_bounds__(256) void k_gemm128(
    const unsigned short* __restrict__ A, int lda,
    const unsigned short* __restrict__ B,
    const float* __restrict__ bias,
    unsigned short* __restrict__ C, int ldc,
    int M, int N, int K, int act) {
  __shared__ unsigned short As[128 * 32];
  __shared__ unsigned short Bs[128 * 32];

  const int id  = blockIdx.y * gridDim.x + blockIdx.x;
  const int nn  = gridDim.x;
  const int sid = id >> 3;
  const int jn  = sid % nn;
  const int im  = (id & 7) + ((sid / nn) << 3);
  if (im >= ((M + 127) >> 7)) return;
  const int m0 = im * 128;
  const int n0 = jn * 128;

  const int tid    = threadIdx.x;
  const int lane   = tid & 63;
  const int w      = tid >> 6;
  const int m_lane = lane & 15;
  const int quad   = lane >> 4;
  const int wm     = (w >> 1) * 64;
  const int wn     = (w & 1) * 64;

  const int idx0 = tid, idx1 = 256 + tid;
  const int kc = (((tid & 3) ^ ((tid >> 3) & 3))) * 8;   // same for idx0/idx1
  int rowA0 = m0 + (idx0 >> 2); if (rowA0 >= M) rowA0 = M - 1;
  int rowA1 = m0 + (idx1 >> 2); if (rowA1 >= M) rowA1 = M - 1;
  const unsigned short* gA0 = A + (size_t)rowA0 * lda + kc;
  const unsigned short* gA1 = A + (size_t)rowA1 * lda + kc;
  const unsigned short* gB0 = B + (size_t)(n0 + (idx0 >> 2)) * K + kc;
  const unsigned short* gB1 = B + (size_t)(n0 + (idx1 >> 2)) * K + kc;

  unsigned short* lA0 = As + (size_t)(w * 64) * 8;
  unsigned short* lA1 = As + (size_t)(256 + w * 64) * 8;
  unsigned short* lB0 = Bs + (size_t)(w * 64) * 8;
  unsigned short* lB1 = Bs + (size_t)(256 + w * 64) * 8;

  const int swz = (quad ^ ((m_lane >> 1) & 3)) * 8;

  f32x4 acc[4][4] = {};

  for (int k0 = 0; k0 < K; k0 += 32) {
    load_lds16(gA0, lA0);
    load_lds16(gA1, lA1);
    load_lds16(gB0, lB0);
    load_lds16(gB1, lB1);
    gA0 += 32; gA1 += 32; gB0 += 32; gB1 += 32;
    __syncthreads();

    bf16x8 af[4], bg[4];
#pragma unroll
    for (int i = 0; i < 4; ++i)
      af[i] = *reinterpret_cast<const bf16x8*>(As + (wm + i * 16 + m_lane) * 32 + swz);
#pragma unroll
    for (int j = 0; j < 4; ++j)
      bg[j] = *reinterpret_cast<const bf16x8*>(Bs + (wn + j * 16 + m_lane) * 32 + swz);
#pragma unroll
    for (int i = 0; i < 4; ++i)
#pragma unroll
      for (int j = 0; j < 4; ++j)
        acc[i][j] = __builtin_amdgcn_mfma_f32_16x16x32_bf16(af[i], bg[j], acc[i][j], 0, 0, 0);
    __syncthreads();
  }

#pragma unroll
  for (int i = 0; i < 4; ++i) {
#pragma unroll
    for (int j = 0; j < 4; ++j) {
      int col = n0 + wn + j * 16 + m_lane;
      float bv = bias ? bias[col] : 0.f;
#pragma unroll
      for (int r = 0; r < 4; ++r) {
        int row = m0 + wm + i * 16 + quad * 4 + r;
        if (row < M) {
          float v = acc[i][j][r] + bv;
          if (act) v = v > 0.f ? v : 0.f;
          C[(size_t)row * ldc + col] = f2bf(v);
        }
      }
    }
  }
}

// ---------------- fused GEMM(+bias+residual)+LayerNorm, N=256 exactly ----------------
// 64-row blocks, 4 waves each owning a 32x128 sub-tile (2 A-frags x 8 B-frags ->
// 16 MFMA per 10 ds_reads). LN row stats combined across the two col-halves via LDS.

__global__ __launch_bounds__(256) void k_gemm_ln(
    const unsigned short* __restrict__ A, int lda,
    const unsigned short* __restrict__ B,           // [256 x K]
    const float* __restrict__ bias,                 // [256]
    const unsigned short* __restrict__ R, int ldr,  // residual bf16 [M x ldr]
    const float* __restrict__ gam, const float* __restrict__ bet,
    unsigned short* __restrict__ C, int ldc,
    int M, int K) {
  __shared__ unsigned short As[64 * 32];    // 4 KB
  __shared__ unsigned short Bs[256 * 32];   // 16 KB
  __shared__ float sSum[2][64];
  __shared__ float sSq[2][64];

  const int tid  = threadIdx.x;
  const int lane = tid & 63;
  const int w    = tid >> 6;
  const int ml   = lane & 15;
  const int quad = lane >> 4;
  const int m0   = blockIdx.x * 64;
  const int rb   = (w & 1) * 32;     // wave row base within tile
  const int cb   = (w >> 1) * 128;   // wave col base

  int arow = m0 + (tid >> 2); if (arow >= M) arow = M - 1;
  const int kcs = ((tid & 3) ^ ((tid >> 3) & 3)) * 8;
  const unsigned short* gA = A + (size_t)arow * lda + kcs;
  const unsigned short* gB0 = B + (size_t)((0 * 256 + tid) >> 2) * K + kcs;
  const unsigned short* gB1 = B + (size_t)((1 * 256 + tid) >> 2) * K + kcs;
  const unsigned short* gB2 = B + (size_t)((2 * 256 + tid) >> 2) * K + kcs;
  const unsigned short* gB3 = B + (size_t)((3 * 256 + tid) >> 2) * K + kcs;

  unsigned short* lA  = As + (size_t)(w * 64) * 8;
  unsigned short* lB0 = Bs + (size_t)(0 * 256 + w * 64) * 8;
  unsigned short* lB1 = Bs + (size_t)(1 * 256 + w * 64) * 8;
  unsigned short* lB2 = Bs + (size_t)(2 * 256 + w * 64) * 8;
  unsigned short* lB3 = Bs + (size_t)(3 * 256 + w * 64) * 8;

  const int swz = (quad ^ ((ml >> 1) & 3)) * 8;

  f32x4 acc[2][8] = {};

  for (int k0 = 0; k0 < K; k0 += 32) {
    load_lds16(gA,  lA);
    load_lds16(gB0, lB0);
    load_lds16(gB1, lB1);
    load_lds16(gB2, lB2);
    load_lds16(gB3, lB3);
    gA += 32; gB0 += 32; gB1 += 32; gB2 += 32; gB3 += 32;
    __syncthreads();

    bf16x8 af[2], bg[8];
#pragma unroll
    for (int i = 0; i < 2; ++i)
      af[i] = *reinterpret_cast<const bf16x8*>(As + (rb + i * 16 + ml) * 32 + swz);
#pragma unroll
    for (int j = 0; j < 8; ++j)
      bg[j] = *reinterpret_cast<const bf16x8*>(Bs + (cb + j * 16 + ml) * 32 + swz);
#pragma unroll
    for (int i = 0; i < 2; ++i)
#pragma unroll
      for (int j = 0; j < 8; ++j)
        acc[i][j] = __builtin_amdgcn_mfma_f32_16x16x32_bf16(af[i], bg[j], acc[i][j], 0, 0, 0);
    __syncthreads();
  }

  // bias + residual; per-row partial stats over this wave's 128 cols
#pragma unroll
  for (int i = 0; i < 2; ++i)
#pragma unroll
    for (int r = 0; r < 4; ++r) {
      int rw = rb + i * 16 + quad * 4 + r;
      int row = m0 + rw;
      int rr2 = row < M ? row : M - 1;
      float s = 0.f, s2 = 0.f;
#pragma unroll
      for (int j = 0; j < 8; ++j) {
        int col = cb + j * 16 + ml;
        float t = acc[i][j][r] + bias[col] + bf2f(R[(size_t)rr2 * ldr + col]);
        acc[i][j][r] = t;
        s += t; s2 += t * t;
      }
#pragma unroll
      for (int o = 1; o < 16; o <<= 1) {
        s  += __shfl_xor(s, o);
        s2 += __shfl_xor(s2, o);
      }
      if (ml == 0) { sSum[w >> 1][rw] = s; sSq[w >> 1][rw] = s2; }
    }
  __syncthreads();

#pragma unroll
  for (int i = 0; i < 2; ++i)
#pragma unroll
    for (int r = 0; r < 4; ++r) {
      int rw = rb + i * 16 + quad * 4 + r;
      int row = m0 + rw;
      if (row >= M) continue;
      float s  = sSum[0][rw] + sSum[1][rw];
      float s2 = sSq[0][rw]  + sSq[1][rw];
      float mean = s * (1.f / 256.f);
      float var  = s2 * (1.f / 256.f) - mean * mean;
      float inv  = rsqrtf(var + 1e-5f);
#pragma unroll
      for (int j = 0; j < 8; ++j) {
        int col = cb + j * 16 + ml;
        C[(size_t)row * ldc + col] = f2bf((acc[i][j][r] - mean) * inv * gam[col] + bet[col]);
      }
    }
}

// ---------------- transformer pieces (bf16 activations, dense layouts) ----------------

__global__ void k_seqbuild(const unsigned short* __restrict__ x1,
                           const unsigned short* __restrict__ x2,
                           const float* __restrict__ cls, const float* __restrict__ pos,
                           unsigned short* __restrict__ seqc, int n0, int cn) {
  int idx = blockIdx.x * blockDim.x + threadIdx.x;
  int total = cn * 3 * DD;
  if (idx >= total) return;
  int c = idx & (DD - 1);
  int r = idx >> 8;
  int t = r % 3, ln = r / 3;
  int n = n0 + ln;
  float v;
  if (t == 0)      v = cls[c];
  else if (t == 1) v = bf2f(x1[(size_t)n * DD + c]);
  else             v = bf2f(x2[(size_t)n * DD + c]);
  seqc[idx] = f2bf(v + pos[t * DD + c]);
}

// qkv: [3 rows x 768] per node; attention output overwrites the q slot in place.
__global__ __launch_bounds__(256) void k_attn(unsigned short* __restrict__ qkvb) {
  __shared__ float qkv[3][768];
  __shared__ float lg[4][3][3];
  __shared__ float aw[4][3][3];
  int tid = threadIdx.x;
  size_t r0 = (size_t)blockIdx.x * 3;
  for (int i = tid; i < 3 * 768; i += 256) {
    int r = i / 768, c = i % 768;
    qkv[r][c] = bf2f(qkvb[(r0 + r) * 768 + c]);
  }
  __syncthreads();
  int h = tid >> 6, lane = tid & 63;
#pragma unroll
  for (int ti = 0; ti < 3; ++ti)
#pragma unroll
    for (int j = 0; j < 3; ++j) {
      float p = qkv[ti][h * 64 + lane] * qkv[j][256 + h * 64 + lane];
      for (int off = 32; off; off >>= 1) p += __shfl_xor(p, off);
      if (lane == 0) lg[h][ti][j] = p * 0.125f;
    }
  __syncthreads();
  if (lane < 3) {
    int ti = lane;
    float l0 = lg[h][ti][0], l1 = lg[h][ti][1], l2 = lg[h][ti][2];
    float m = fmaxf(l0, fmaxf(l1, l2));
    float e0 = __expf(l0 - m), e1 = __expf(l1 - m), e2 = __expf(l2 - m);
    float inv = 1.f / (e0 + e1 + e2);
    aw[h][ti][0] = e0 * inv; aw[h][ti][1] = e1 * inv; aw[h][ti][2] = e2 * inv;
  }
  __syncthreads();
  int c = tid;
#pragma unroll
  for (int ti = 0; ti < 3; ++ti) {
    float o = aw[h][ti][0] * qkv[0][512 + c] +
              aw[h][ti][1] * qkv[1][512 + c] +
              aw[h][ti][2] * qkv[2][512 + c];
    qkvb[(r0 + ti) * 768 + c] = f2bf(o);   // overwrite q slot
  }
}

__global__ __launch_bounds__(256) void k_final(const unsigned short* __restrict__ seqc,
                                               int n0, int cn,
                                               const float* __restrict__ g,
                                               const float* __restrict__ b,
                                               float* __restrict__ out) {
  int ln = blockIdx.x * 4 + (threadIdx.x >> 6);
  if (ln >= cn) return;
  int lane = threadIdx.x & 63;
  const unsigned short* p = seqc + (size_t)ln * 3 * DD;   // token 0 row
  float v[4];
  float s = 0.f, s2 = 0.f;
#pragma unroll
  for (int i = 0; i < 4; ++i) {
    v[i] = bf2f(p[i * 64 + lane]);
    s += v[i]; s2 += v[i] * v[i];
  }
  for (int off = 32; off; off >>= 1) { s += __shfl_xor(s, off); s2 += __shfl_xor(s2, off); }
  float mean = s * (1.f / 256.f);
  float var  = s2 * (1.f / 256.f) - mean * mean;
  float inv  = rsqrtf(var + 1e-5f);
#pragma unroll
  for (int i = 0; i < 4; ++i) {
    int c = i * 64 + lane;
    out[(size_t)(n0 + ln) * DD + c] = (v[i] - mean) * inv * g[c] + b[c];
  }
}

// ---------------- host ----------------

extern "C" void kernel_launch(void* const* d_in, const int* in_sizes, int n_in,
                              void* d_out, int out_size, void* d_ws, size_t ws_size,
                              hipStream_t stream) {
  const float* x       = (const float*)d_in[0];
  const int*   ei      = (const int*)d_in[1];
  const float* gat1_W  = (const float*)d_in[2];
  const float* gat1_b  = (const float*)d_in[3];
  const float* gat1_as = (const float*)d_in[4];
  const float* gat1_ad = (const float*)d_in[5];
  const float* gat2_W  = (const float*)d_in[6];
  const float* gat2_b  = (const float*)d_in[7];
  const float* gat2_as = (const float*)d_in[8];
  const float* gat2_ad = (const float*)d_in[9];
  const float* cls     = (const float*)d_in[10];
  const float* pos     = (const float*)d_in[11];
  const float* Wqkv    = (const float*)d_in[12];
  const float* bqkv    = (const float*)d_in[13];
  const float* Wo      = (const float*)d_in[14];
  const float* bo      = (const float*)d_in[15];
  const float* ln1_g   = (const float*)d_in[16];
  const float* ln1_b   = (const float*)d_in[17];
  const float* ln2_g   = (const float*)d_in[18];
  const float* ln2_b   = (const float*)d_in[19];
  const float* Wff1    = (const float*)d_in[20];
  const float* bff1    = (const float*)d_in[21];
  const float* Wff2    = (const float*)d_in[22];
  const float* bff2    = (const float*)d_in[23];
  const float* norm_g  = (const float*)d_in[24];
  const float* norm_b  = (const float*)d_in[25];
  float* out = (float*)d_out;

  char* ws = (char*)d_ws;
  size_t off = 0;
  auto alloc = [&](size_t bytes) -> void* {
    off = (off + 255) & ~(size_t)255;
    void* p = ws + off;
    off += bytes;
    return p;
  };

  unsigned short* wb_g1  = (unsigned short*)alloc(sizeof(unsigned short) * 256 * 128);
  unsigned short* wb_g2  = (unsigned short*)alloc(sizeof(unsigned short) * 256 * 256);
  unsigned short* wb_qkv = (unsigned short*)alloc(sizeof(unsigned short) * 2 * 768 * 256);
  unsigned short* wb_o   = (unsigned short*)alloc(sizeof(unsigned short) * 2 * 256 * 256);
  unsigned short* wb_f1  = (unsigned short*)alloc(sizeof(unsigned short) * 2 * 1024 * 256);
  unsigned short* wb_f2  = (unsigned short*)alloc(sizeof(unsigned short) * 2 * 256 * 1024);
  unsigned short* xb  = (unsigned short*)alloc(sizeof(unsigned short) * (size_t)NN * DIN);
  unsigned short* hb  = (unsigned short*)alloc(sizeof(unsigned short) * (size_t)NN * DD);
  unsigned short* x1b = (unsigned short*)alloc(sizeof(unsigned short) * (size_t)NN * DD);
  unsigned short* x2b = (unsigned short*)alloc(sizeof(unsigned short) * (size_t)NN * DD);
  float* hs  = (float*)alloc(sizeof(float) * NN);
  float* hd  = (float*)alloc(sizeof(float) * NN);
  int* deg   = (int*)alloc(sizeof(int) * NN);
  int* inc   = (int*)alloc(sizeof(int) * NN);
  int* cur   = (int*)alloc(sizeof(int) * NN);
  int* tsum  = (int*)alloc(sizeof(int) * 64);
  int* ssrc  = (int*)alloc(sizeof(int) * E2);

  // transformer chunking (L3 residency of per-chunk activations)
  size_t fixed = (off + 255) & ~(size_t)255;
  size_t rem = (ws_size > fixed + 4096) ? (ws_size - fixed - 4096) : 0;
  const size_t per_node = (size_t)3 * (256 + 768 + 1024) * 2;
  size_t cn_max = rem / per_node;
  if (cn_max < 1) cn_max = 1;
  if (cn_max > 12500) cn_max = 12500;
  int nc = (int)((NN + cn_max - 1) / cn_max);
  int cn = (NN + nc - 1) / nc;
  unsigned short* seqc = (unsigned short*)alloc(sizeof(unsigned short) * (size_t)3 * cn * 256);
  unsigned short* qkvb = (unsigned short*)alloc(sizeof(unsigned short) * (size_t)3 * cn * 768);
  unsigned short* ffb  = (unsigned short*)alloc(sizeof(unsigned short) * (size_t)3 * cn * 1024);

  // ---- casts ----
  auto cast = [&](const float* src, unsigned short* dst, int n) {
    k_cast<<<(n + 255) / 256, 256, 0, stream>>>(src, dst, n);
  };
  cast(gat1_W, wb_g1, 256 * 128);
  cast(gat2_W, wb_g2, 256 * 256);
  cast(Wqkv, wb_qkv, 2 * 768 * 256);
  cast(Wo, wb_o, 2 * 256 * 256);
  cast(Wff1, wb_f1, 2 * 1024 * 256);
  cast(Wff2, wb_f2, 2 * 256 * 1024);
  cast(x, xb, NN * DIN);

  // ---- CSR build ----
  hipMemsetAsync(deg, 0, sizeof(int) * NN, stream);
  hipMemsetAsync(cur, 0, sizeof(int) * NN, stream);
  k_deg<<<(E2 + 255) / 256, 256, 0, stream>>>(ei, deg);
  int nb = (NN + 1023) / 1024;
  k_scan_tile<<<nb, 1024, 0, stream>>>(deg, inc, tsum, NN);
  k_scan_sums<<<1, 64, 0, stream>>>(tsum, nb);
  k_scan_add<<<(NN + 255) / 256, 256, 0, stream>>>(inc, tsum, NN);
  k_scatter<<<(E2 + 255) / 256, 256, 0, stream>>>(ei, deg, inc, cur, ssrc);

  auto gemm = [&](const unsigned short* A, int lda, const unsigned short* B,
                  const float* bias, unsigned short* C, int ldc,
                  int M, int N, int K, int act) {
    int nm = (M + 127) / 128;
    int nmp = (nm + 7) & ~7;
    dim3 grid(N / 128, nmp);
    k_gemm128<<<grid, 256, 0, stream>>>(A, lda, B, bias, C, ldc, M, N, K, act);
  };

  // ---- GAT layer 1: hb = xb @ W1^T (K=128) ----
  gemm(xb, DIN, wb_g1, nullptr, hb, DD, NN, DD, DIN, 0);
  k_dots<<<(NN + 3) / 4, 256, 0, stream>>>(hb, gat1_as, gat1_ad, hs, hd);
  k_gat<<<(NN + 3) / 4, 256, 0, stream>>>(hb, ssrc, deg, inc, hs, hd, gat1_b, x1b);

  // ---- GAT layer 2: hb = x1b @ W2^T (K=256) ----
  gemm(x1b, DD, wb_g2, nullptr, hb, DD, NN, DD, DD, 0);
  k_dots<<<(NN + 3) / 4, 256, 0, stream>>>(hb, gat2_as, gat2_ad, hs, hd);
  k_gat<<<(NN + 3) / 4, 256, 0, stream>>>(hb, ssrc, deg, inc, hs, hd, gat2_b, x2b);

  // ---- transformer (chunked) ----
  for (int n0 = 0; n0 < NN; n0 += cn) {
    int c = NN - n0 < cn ? NN - n0 : cn;
    int Mch = 3 * c;
    int mblk64 = (Mch + 63) / 64;
    k_seqbuild<<<(c * 3 * DD + 255) / 256, 256, 0, stream>>>(x1b, x2b, cls, pos, seqc, n0, c);
    for (int l = 0; l < 2; ++l) {
      // qkv: N=768, K=256
      gemm(seqc, DD, wb_qkv + (size_t)l * 768 * 256, bqkv + l * 768,
           qkvb, 768, Mch, 768, DD, 0);
      k_attn<<<c, 256, 0, stream>>>(qkvb);
      // o-proj + residual + ln1 fused (K=256)
      k_gemm_ln<<<mblk64, 256, 0, stream>>>(
          qkvb, 768, wb_o + (size_t)l * 256 * 256, bo + l * 256,
          seqc, DD, ln1_g + l * 256, ln1_b + l * 256, seqc, DD, Mch, DD);
      // ff1: N=1024, K=256, relu
      gemm(seqc, DD, wb_f1 + (size_t)l * 1024 * 256, bff1 + l * 1024,
           ffb, 1024, Mch, 1024, DD, 1);
      // ff2 + residual + ln2 fused (K=1024)
      k_gemm_ln<<<mblk64, 256, 0, stream>>>(
          ffb, 1024, wb_f2 + (size_t)l * 256 * 1024, bff2 + l * 256,
          seqc, DD, ln2_g + l * 256, ln2_b + l * 256, seqc, DD, Mch, 1024);
    }
    k_final<<<(c + 3) / 4, 256, 0, stream>>>(seqc, n0, c, norm_g, norm_b, out);
  }
}